// Round 23
// baseline (122.146 us; speedup 1.0000x reference)
//
#include <hip/hip_runtime.h>

typedef __attribute__((ext_vector_type(8))) _Float16 f16x8;
typedef __attribute__((ext_vector_type(4))) _Float16 f16x4;
typedef __attribute__((ext_vector_type(2))) _Float16 f16x2;
typedef __attribute__((ext_vector_type(2))) __fp16   fp16x2_raw;
typedef __attribute__((ext_vector_type(4))) float    f32x4;

#define NUM_HEADS 16
#define HEAD_D 64
#define EMB 1024
#define SEQ 2048
#define BATCH 2
#define MTOT (BATCH * SEQ) // 4096

// Q scale: 1/sqrt(64) * log2(e)  (softmax runs in exp2 domain)
#define QALPHA 0.18033688011112042f

__device__ __forceinline__ f16x2 cvt_pk_f16(float lo, float hi)
{
    fp16x2_raw r = __builtin_amdgcn_cvt_pkrtz(lo, hi);
    return __builtin_bit_cast(f16x2, r);
}

// Raw v_exp_f32 (2^x). Guarded: fall back to fast __expf if builtin absent.
#if defined(__has_builtin)
#if __has_builtin(__builtin_amdgcn_exp2f)
#define HAVE_EXP2 1
#endif
#endif
__device__ __forceinline__ float fast_exp2(float x)
{
#ifdef HAVE_EXP2
    return __builtin_amdgcn_exp2f(x);
#else
    return __expf(x * 0.6931471805599453f);
#endif
}

// ---------------------------------------------------------------------------
// global -> LDS direct staging (16 B per lane). LDS dest is wave-uniform
// base + lane*16 (HW behavior); fallback reg-stages to the same address.
// ---------------------------------------------------------------------------
#if defined(__has_builtin)
#if __has_builtin(__builtin_amdgcn_global_load_lds)
#define HAVE_GLOAD_LDS 1
#endif
#endif

__device__ __forceinline__ void stage16(const void* g, void* ldsWaveBase, int lane)
{
#ifdef HAVE_GLOAD_LDS
    __builtin_amdgcn_global_load_lds(
        (const __attribute__((address_space(1))) void*)g,
        (__attribute__((address_space(3))) void*)ldsWaveBase, 16, 0, 0);
    (void)lane;
#else
    *(f16x8*)((char*)ldsWaveBase + lane * 16) = *(const f16x8*)g;
#endif
}

// ---------------------------------------------------------------------------
// Fused prep: grid (32,32,5), 256 threads.
//  z=0..3 : transpose+cast W (z<3 -> Wt + z*WE, z=3 -> Wto)
//  z=4    : cast x -> xh (2 f16x8 chunks per thread)
// ---------------------------------------------------------------------------
__global__ __launch_bounds__(256) void prep_all(
    const float* __restrict__ x,
    const float* __restrict__ Wq, const float* __restrict__ Wk,
    const float* __restrict__ Wv, const float* __restrict__ Wo,
    _Float16* __restrict__ xh, _Float16* __restrict__ Wt,
    _Float16* __restrict__ Wto)
{
    const int z = blockIdx.z;
    if (z == 4) {
        int base = ((blockIdx.y * 32 + blockIdx.x) * 256 + threadIdx.x) * 2;
        #pragma unroll
        for (int t = 0; t < 2; ++t) {
            int i = base + t;
            float4 a = ((const float4*)x)[i * 2];
            float4 b = ((const float4*)x)[i * 2 + 1];
            f16x8 o;
            o[0] = (_Float16)a.x; o[1] = (_Float16)a.y;
            o[2] = (_Float16)a.z; o[3] = (_Float16)a.w;
            o[4] = (_Float16)b.x; o[5] = (_Float16)b.y;
            o[6] = (_Float16)b.z; o[7] = (_Float16)b.w;
            ((f16x8*)xh)[i] = o;
        }
        return;
    }
    const float* W = z == 0 ? Wq : (z == 1 ? Wk : (z == 2 ? Wv : Wo));
    _Float16* D = (z == 3) ? Wto : (Wt + (size_t)z * EMB * EMB);
    __shared__ float tile[32][33];
    const int tx = threadIdx.x & 31, ty = threadIdx.x >> 5; // (32, 8)
    const int n0 = blockIdx.x * 32, k0 = blockIdx.y * 32;
    #pragma unroll
    for (int j = 0; j < 4; ++j)
        tile[ty + j * 8][tx] = W[(size_t)(k0 + ty + j * 8) * EMB + n0 + tx];
    __syncthreads();
    #pragma unroll
    for (int j = 0; j < 4; ++j)
        D[(size_t)(n0 + ty + j * 8) * EMB + k0 + tx] =
            (_Float16)tile[tx][ty + j * 8];
}

// ---------------------------------------------------------------------------
// Fused QKV GEMM: [4096, 3072] = xh @ Wt^T. 128x128 tile, BK=32, 4 waves.
// R19 form (measured best). XCD swizzle col-major.
// Q,K written [B,H,T,D] (Q scaled by QALPHA); V written transposed [B,H,D,T].
// ---------------------------------------------------------------------------
__global__ __launch_bounds__(256) void gemm_qkv(
    const _Float16* __restrict__ A, const _Float16* __restrict__ Bt,
    _Float16* __restrict__ Qh, _Float16* __restrict__ Kh,
    _Float16* __restrict__ VhT)
{
    __shared__ __align__(16) _Float16 As[128 * 32]; // 8 KB
    __shared__ __align__(16) _Float16 Bs[128 * 32]; // 8 KB

    const int tid = threadIdx.x;
    const int w = tid >> 6, lane = tid & 63;
    const int l15 = lane & 15, g4 = lane >> 4;
    const int wm = w >> 1, wn = w & 1;

    // XCD-aware bijective remap (nwg = 768, 768 % 8 == 0)
    const int wg = blockIdx.y * gridDim.x + blockIdx.x;
    const int t  = (wg & 7) * 96 + (wg >> 3);
    const int bx = t >> 5, by = t & 31;     // col-major tile order
    const int row0 = by * 128, col0 = bx * 128;

    f32x4 acc[4][4];
    #pragma unroll
    for (int mt = 0; mt < 4; ++mt)
        #pragma unroll
        for (int nt = 0; nt < 4; ++nt)
            acc[mt][nt] = (f32x4){0.f, 0.f, 0.f, 0.f};

    for (int k0 = 0; k0 < EMB; k0 += 32) {
        __syncthreads();
        #pragma unroll
        for (int i = 0; i < 2; ++i) {
            int c = (i << 8) + tid;
            int row = c >> 2, u = c & 3;
            stage16(&A[(size_t)(row0 + row) * EMB + k0 + (u << 3)],
                    (char*)As + (i << 12) + (w << 10), lane);
            stage16(&Bt[(size_t)(col0 + row) * EMB + k0 + (u << 3)],
                    (char*)Bs + (i << 12) + (w << 10), lane);
        }
        __syncthreads();

        f16x8 af[4], bf[4];
        #pragma unroll
        for (int mt = 0; mt < 4; ++mt)
            af[mt] = *(const f16x8*)((const char*)As +
                     ((wm << 6) + (mt << 4) + l15) * 64 + (g4 << 4));
        #pragma unroll
        for (int nt = 0; nt < 4; ++nt)
            bf[nt] = *(const f16x8*)((const char*)Bs +
                     ((wn << 6) + (nt << 4) + l15) * 64 + (g4 << 4));
        #pragma unroll
        for (int mt = 0; mt < 4; ++mt)
            #pragma unroll
            for (int nt = 0; nt < 4; ++nt)
                acc[mt][nt] = __builtin_amdgcn_mfma_f32_16x16x32_f16(
                    af[mt], bf[nt], acc[mt][nt], 0, 0, 0);
    }

    // Epilogue. C/D: col = lane&15, row = 4*(lane>>4) + reg.
    #pragma unroll
    for (int mt = 0; mt < 4; ++mt) {
        int m = row0 + (wm << 6) + (mt << 4) + (g4 << 2);
        #pragma unroll
        for (int nt = 0; nt < 4; ++nt) {
            int gcol = col0 + (wn << 6) + (nt << 4) + l15;
            int proj = gcol >> 10, pc = gcol & 1023;
            int h = pc >> 6, d = pc & 63;
            int b = m >> 11, tt = m & 2047;
            int bh = b * NUM_HEADS + h;
            if (proj == 2) {
                f16x4 v4;
                v4[0] = (_Float16)acc[mt][nt][0];
                v4[1] = (_Float16)acc[mt][nt][1];
                v4[2] = (_Float16)acc[mt][nt][2];
                v4[3] = (_Float16)acc[mt][nt][3];
                *(f16x4*)&VhT[((size_t)bh * HEAD_D + d) * SEQ + tt] = v4;
            } else {
                _Float16* dst = proj == 0 ? Qh : Kh;
                float alpha = proj == 0 ? QALPHA : 1.0f;
                #pragma unroll
                for (int r = 0; r < 4; ++r)
                    dst[((size_t)bh * SEQ + tt + r) * HEAD_D + d] =
                        (_Float16)(acc[mt][nt][r] * alpha);
            }
        }
    }
}

// ---------------------------------------------------------------------------
// Output projection GEMM: [4096, 1024] fp32 + bias. 128x64 tile (512 blocks
// = 2/CU), BK=32 (R19 form), 4 waves, wave tile 64x32. XCD swizzle.
// ---------------------------------------------------------------------------
__global__ __launch_bounds__(256) void gemm_out(
    const _Float16* __restrict__ A, const _Float16* __restrict__ Bt,
    float* __restrict__ outf, const float* __restrict__ bias)
{
    __shared__ __align__(16) _Float16 As[128 * 32]; // 8 KB
    __shared__ __align__(16) _Float16 Bs[64 * 32];  // 4 KB

    const int tid = threadIdx.x;
    const int w = tid >> 6, lane = tid & 63;
    const int l15 = lane & 15, g4 = lane >> 4;
    const int wm = w >> 1, wn = w & 1;

    const int wg = blockIdx.y * gridDim.x + blockIdx.x;
    const int t  = (wg & 7) * 64 + (wg >> 3);
    const int bx = t >> 5, by = t & 31;
    const int row0 = by * 128, col0 = bx * 64;

    f32x4 acc[4][2];
    #pragma unroll
    for (int mt = 0; mt < 4; ++mt)
        #pragma unroll
        for (int nt = 0; nt < 2; ++nt)
            acc[mt][nt] = (f32x4){0.f, 0.f, 0.f, 0.f};

    for (int k0 = 0; k0 < EMB; k0 += 32) {
        __syncthreads();
        #pragma unroll
        for (int i = 0; i < 2; ++i) {
            int c = (i << 8) + tid;
            int row = c >> 2, u = c & 3;
            stage16(&A[(size_t)(row0 + row) * EMB + k0 + (u << 3)],
                    (char*)As + (i << 12) + (w << 10), lane);
        }
        {
            int row = tid >> 2, u = tid & 3; // 256 chunks: 64 rows x 4 units
            stage16(&Bt[(size_t)(col0 + row) * EMB + k0 + (u << 3)],
                    (char*)Bs + (w << 10), lane);
        }
        __syncthreads();

        f16x8 af[4], bf[2];
        #pragma unroll
        for (int mt = 0; mt < 4; ++mt)
            af[mt] = *(const f16x8*)((const char*)As +
                     ((wm << 6) + (mt << 4) + l15) * 64 + (g4 << 4));
        #pragma unroll
        for (int nt = 0; nt < 2; ++nt)
            bf[nt] = *(const f16x8*)((const char*)Bs +
                     ((wn << 5) + (nt << 4) + l15) * 64 + (g4 << 4));
        #pragma unroll
        for (int mt = 0; mt < 4; ++mt)
            #pragma unroll
            for (int nt = 0; nt < 2; ++nt)
                acc[mt][nt] = __builtin_amdgcn_mfma_f32_16x16x32_f16(
                    af[mt], bf[nt], acc[mt][nt], 0, 0, 0);
    }

    #pragma unroll
    for (int mt = 0; mt < 4; ++mt) {
        int m = row0 + (wm << 6) + (mt << 4) + (g4 << 2);
        #pragma unroll
        for (int nt = 0; nt < 2; ++nt) {
            int gcol = col0 + (wn << 5) + (nt << 4) + l15;
            float bz = bias[gcol];
            #pragma unroll
            for (int r = 0; r < 4; ++r)
                outf[(size_t)(m + r) * EMB + gcol] = acc[mt][nt][r] + bz;
        }
    }
}

// ---------------------------------------------------------------------------
// Stage one 64-kv K tile + V^T tile into LDS via global_load_lds with
// pre-swizzled global source (LDS dest linear; chunk (row,u) holds global
// (row, u^(row&7)) -> read formulas identical to the verified K-frag path).
// ---------------------------------------------------------------------------
__device__ __forceinline__ void stage_kv_tile(
    const _Float16* __restrict__ KhB, const _Float16* __restrict__ VtB,
    int kv0, char* __restrict__ KsBuf, char* __restrict__ VtBuf,
    int w, int lane)
{
    #pragma unroll
    for (int i = 0; i < 2; ++i) {
        int c = (i << 8) + (w << 6) + lane;
        int row = c >> 3, u = c & 7;
        int us = u ^ (row & 7);
        stage16(&KhB[(size_t)(kv0 + row) * HEAD_D + (us << 3)],
                KsBuf + (i << 12) + (w << 10), lane);
        stage16(&VtB[(size_t)row * SEQ + kv0 + (us << 3)],
                VtBuf + (i << 12) + (w << 10), lane);
    }
}

// ---------------------------------------------------------------------------
// Per-chain softmax update over NT s-registers (verbatim R15 semantics):
// shuffle-free defer-max, per-lane partial l, in-place P = 2^(s-m).
// ---------------------------------------------------------------------------
template <int NT>
__device__ __forceinline__ void softmax_update(
    f32x4 (&s)[NT], f32x4 (&acc)[4], float& m, float& l, int g)
{
    float mx = -1e30f;
    #pragma unroll
    for (int i = 0; i < NT; ++i)
        mx = fmaxf(mx, fmaxf(fmaxf(s[i][0], s[i][1]), fmaxf(s[i][2], s[i][3])));

    if (!__all(mx - m <= 8.0f)) {
        float mxr = fmaxf(mx, __shfl_xor(mx, 16));
        mxr = fmaxf(mxr, __shfl_xor(mxr, 32));
        float nm = fmaxf(m, mxr);
        float sc = fast_exp2(m - nm);   // row-uniform
        m = nm;
        l *= sc;
        #pragma unroll
        for (int r = 0; r < 4; ++r) {
            float scr = __shfl(sc, (g << 2) + r);
            acc[0][r] *= scr; acc[1][r] *= scr;
            acc[2][r] *= scr; acc[3][r] *= scr;
        }
    }

    float ps = 0.f;
    #pragma unroll
    for (int i = 0; i < NT; ++i)
        #pragma unroll
        for (int r = 0; r < 4; ++r) {
            float p = fast_exp2(s[i][r] - m);
            s[i][r] = p;
            ps += p;
        }
    l += ps;
}

// P write (4 f32x4 of one tile) -> wave-private region; returns A-frags.
__device__ __forceinline__ void p_roundtrip(
    const f32x4* s4, char* __restrict__ pwv, int l15, int g,
    f16x8& pa0, f16x8& pa1)
{
    #pragma unroll
    for (int nt = 0; nt < 4; ++nt)
        #pragma unroll
        for (int rr = 0; rr < 2; ++rr) {
            int kvb = (nt << 4) + (g << 2) + (rr << 1);
            f16x2 pv = cvt_pk_f16(s4[nt][rr * 2], s4[nt][rr * 2 + 1]);
            *(f16x2*)&pwv[l15 * 128 + ((kvb << 1) ^ ((l15 & 7) << 4))] = pv;
        }
    pa0 = *(const f16x8*)&pwv[l15 * 128 + (((g << 4)) ^ ((l15 & 7) << 4))];
    pa1 = *(const f16x8*)&pwv[l15 * 128 + ((64 + (g << 4)) ^ ((l15 & 7) << 4))];
}

// ---------------------------------------------------------------------------
// Single 64q x 64kv attention tile step (verified R15 form).
// ---------------------------------------------------------------------------
__device__ __forceinline__ void attn_tile(
    const char* __restrict__ KsC, const char* __restrict__ VtC,
    char* __restrict__ pwv,
    f16x8 qf0, f16x8 qf1, f32x4 (&acc)[4], float& m, float& l,
    bool diag, int qrel, int l15, int g)
{
    f32x4 st[4];
    #pragma unroll
    for (int nt = 0; nt < 4; ++nt) {
        int kvl = (nt << 4) + l15;
        f16x8 kf0 = *(const f16x8*)&KsC[kvl * 128 + (((g << 4)) ^ ((kvl & 7) << 4))];
        f16x8 kf1 = *(const f16x8*)&KsC[kvl * 128 + ((64 + (g << 4)) ^ ((kvl & 7) << 4))];
        f32x4 z = (f32x4){0.f, 0.f, 0.f, 0.f};
        z = __builtin_amdgcn_mfma_f32_16x16x32_f16(kf0, qf0, z, 0, 0, 0);
        z = __builtin_amdgcn_mfma_f32_16x16x32_f16(kf1, qf1, z, 0, 0, 0);
        st[nt] = z;
    }
    if (diag) {
        #pragma unroll
        for (int nt = 0; nt < 4; ++nt)
            #pragma unroll
            for (int r = 0; r < 4; ++r)
                if ((nt << 4) + (g << 2) + r > qrel) st[nt][r] = -1e30f;
    }

    softmax_update<4>(st, acc, m, l, g);

    f16x8 pa0, pa1;
    p_roundtrip(st, pwv, l15, g, pa0, pa1);

    #pragma unroll
    for (int dn = 0; dn < 4; ++dn) {
        int d = (dn << 4) + l15;
        f16x8 vf0 = *(const f16x8*)&VtC[d * 128 + (((g << 4)) ^ ((d & 7) << 4))];
        f16x8 vf1 = *(const f16x8*)&VtC[d * 128 + ((64 + (g << 4)) ^ ((d & 7) << 4))];
        acc[dn] = __builtin_amdgcn_mfma_f32_16x16x32_f16(pa0, vf0, acc[dn], 0, 0, 0);
        acc[dn] = __builtin_amdgcn_mfma_f32_16x16x32_f16(pa1, vf1, acc[dn], 0, 0, 0);
    }
}

// ---------------------------------------------------------------------------
// Dual-chain single-kv step (R22): shared K/V fragments feed both chains.
// diag applies to A only (phase-1 tail).
// ---------------------------------------------------------------------------
__device__ __forceinline__ void attn_tile_dual(
    const char* __restrict__ KsC, const char* __restrict__ VtC,
    char* __restrict__ pwvA, char* __restrict__ pwvB,
    f16x8 qfA0, f16x8 qfA1, f16x8 qfB0, f16x8 qfB1,
    f32x4 (&accA)[4], f32x4 (&accB)[4],
    float& mA, float& lA, float& mB, float& lB,
    bool diagA, int qrel, int l15, int g)
{
    f32x4 sA[4], sB[4];
    #pragma unroll
    for (int nt = 0; nt < 4; ++nt) {
        int kvl = (nt << 4) + l15;
        f16x8 kf0 = *(const f16x8*)&KsC[kvl * 128 + (((g << 4)) ^ ((kvl & 7) << 4))];
        f16x8 kf1 = *(const f16x8*)&KsC[kvl * 128 + ((64 + (g << 4)) ^ ((kvl & 7) << 4))];
        f32x4 zA = (f32x4){0.f, 0.f, 0.f, 0.f};
        zA = __builtin_amdgcn_mfma_f32_16x16x32_f16(kf0, qfA0, zA, 0, 0, 0);
        zA = __builtin_amdgcn_mfma_f32_16x16x32_f16(kf1, qfA1, zA, 0, 0, 0);
        sA[nt] = zA;
        f32x4 zB = (f32x4){0.f, 0.f, 0.f, 0.f};
        zB = __builtin_amdgcn_mfma_f32_16x16x32_f16(kf0, qfB0, zB, 0, 0, 0);
        zB = __builtin_amdgcn_mfma_f32_16x16x32_f16(kf1, qfB1, zB, 0, 0, 0);
        sB[nt] = zB;
    }
    if (diagA) {
        #pragma unroll
        for (int nt = 0; nt < 4; ++nt)
            #pragma unroll
            for (int r = 0; r < 4; ++r)
                if ((nt << 4) + (g << 2) + r > qrel) sA[nt][r] = -1e30f;
    }

    softmax_update<4>(sA, accA, mA, lA, g);
    softmax_update<4>(sB, accB, mB, lB, g);

    f16x8 paA0, paA1, paB0, paB1;
    p_roundtrip(sA, pwvA, l15, g, paA0, paA1);
    p_roundtrip(sB, pwvB, l15, g, paB0, paB1);

    #pragma unroll
    for (int dn = 0; dn < 4; ++dn) {
        int d = (dn << 4) + l15;
        f16x8 vf0 = *(const f16x8*)&VtC[d * 128 + (((g << 4)) ^ ((d & 7) << 4))];
        f16x8 vf1 = *(const f16x8*)&VtC[d * 128 + ((64 + (g << 4)) ^ ((d & 7) << 4))];
        accA[dn] = __builtin_amdgcn_mfma_f32_16x16x32_f16(paA0, vf0, accA[dn], 0, 0, 0);
        accA[dn] = __builtin_amdgcn_mfma_f32_16x16x32_f16(paA1, vf1, accA[dn], 0, 0, 0);
        accB[dn] = __builtin_amdgcn_mfma_f32_16x16x32_f16(paB0, vf0, accB[dn], 0, 0, 0);
        accB[dn] = __builtin_amdgcn_mfma_f32_16x16x32_f16(paB1, vf1, accB[dn], 0, 0, 0);
    }
}

// ---------------------------------------------------------------------------
// R23: dual-chain DUAL-kv step for phase-1 pairs — 2 kv tiles x 2 chains per
// barrier. Merged per-chain softmax over both tiles (tile2 semantics);
// shared K/V fragments between chains (tile_dual pattern). diagA only ever
// on the SECOND tile (kt+1 == qtA).
// ---------------------------------------------------------------------------
__device__ __forceinline__ void attn_tile2_dual(
    const char* __restrict__ Ks0, const char* __restrict__ Vt0,
    const char* __restrict__ Ks1, const char* __restrict__ Vt1,
    char* __restrict__ pwvA, char* __restrict__ pwvB,
    f16x8 qfA0, f16x8 qfA1, f16x8 qfB0, f16x8 qfB1,
    f32x4 (&accA)[4], f32x4 (&accB)[4],
    float& mA, float& lA, float& mB, float& lB,
    bool diagA1, int qrel, int l15, int g)
{
    f32x4 sA[8], sB[8];
    #pragma unroll
    for (int nt = 0; nt < 4; ++nt) {
        int kvl = (nt << 4) + l15;
        int off0 = kvl * 128 + (((g << 4)) ^ ((kvl & 7) << 4));
        int off1 = kvl * 128 + ((64 + (g << 4)) ^ ((kvl & 7) << 4));
        {
            f16x8 kf0 = *(const f16x8*)&Ks0[off0];
            f16x8 kf1 = *(const f16x8*)&Ks0[off1];
            f32x4 zA = (f32x4){0.f, 0.f, 0.f, 0.f};
            zA = __builtin_amdgcn_mfma_f32_16x16x32_f16(kf0, qfA0, zA, 0, 0, 0);
            zA = __builtin_amdgcn_mfma_f32_16x16x32_f16(kf1, qfA1, zA, 0, 0, 0);
            sA[nt] = zA;
            f32x4 zB = (f32x4){0.f, 0.f, 0.f, 0.f};
            zB = __builtin_amdgcn_mfma_f32_16x16x32_f16(kf0, qfB0, zB, 0, 0, 0);
            zB = __builtin_amdgcn_mfma_f32_16x16x32_f16(kf1, qfB1, zB, 0, 0, 0);
            sB[nt] = zB;
        }
        {
            f16x8 kf0 = *(const f16x8*)&Ks1[off0];
            f16x8 kf1 = *(const f16x8*)&Ks1[off1];
            f32x4 zA = (f32x4){0.f, 0.f, 0.f, 0.f};
            zA = __builtin_amdgcn_mfma_f32_16x16x32_f16(kf0, qfA0, zA, 0, 0, 0);
            zA = __builtin_amdgcn_mfma_f32_16x16x32_f16(kf1, qfA1, zA, 0, 0, 0);
            sA[4 + nt] = zA;
            f32x4 zB = (f32x4){0.f, 0.f, 0.f, 0.f};
            zB = __builtin_amdgcn_mfma_f32_16x16x32_f16(kf0, qfB0, zB, 0, 0, 0);
            zB = __builtin_amdgcn_mfma_f32_16x16x32_f16(kf1, qfB1, zB, 0, 0, 0);
            sB[4 + nt] = zB;
        }
    }
    if (diagA1) {
        #pragma unroll
        for (int nt = 0; nt < 4; ++nt)
            #pragma unroll
            for (int r = 0; r < 4; ++r)
                if ((nt << 4) + (g << 2) + r > qrel) sA[4 + nt][r] = -1e30f;
    }

    softmax_update<8>(sA, accA, mA, lA, g);
    softmax_update<8>(sB, accB, mB, lB, g);

    // PV per tile, both chains sharing V fragments
    #pragma unroll
    for (int tile = 0; tile < 2; ++tile) {
        const char* Vt = tile ? Vt1 : Vt0;
        f16x8 paA0, paA1, paB0, paB1;
        p_roundtrip(&sA[tile << 2], pwvA, l15, g, paA0, paA1);
        p_roundtrip(&sB[tile << 2], pwvB, l15, g, paB0, paB1);
        #pragma unroll
        for (int dn = 0; dn < 4; ++dn) {
            int d = (dn << 4) + l15;
            f16x8 vf0 = *(const f16x8*)&Vt[d * 128 + (((g << 4)) ^ ((d & 7) << 4))];
            f16x8 vf1 = *(const f16x8*)&Vt[d * 128 + ((64 + (g << 4)) ^ ((d & 7) << 4))];
            accA[dn] = __builtin_amdgcn_mfma_f32_16x16x32_f16(paA0, vf0, accA[dn], 0, 0, 0);
            accA[dn] = __builtin_amdgcn_mfma_f32_16x16x32_f16(paA1, vf1, accA[dn], 0, 0, 0);
            accB[dn] = __builtin_amdgcn_mfma_f32_16x16x32_f16(paB0, vf0, accB[dn], 0, 0, 0);
            accB[dn] = __builtin_amdgcn_mfma_f32_16x16x32_f16(paB1, vf1, accB[dn], 0, 0, 0);
        }
    }
}

// ---------------------------------------------------------------------------
// Dual-kv single-chain step (R16 form, for phase 2). diag only SECOND tile.
// ---------------------------------------------------------------------------
__device__ __forceinline__ void attn_tile2(
    const char* __restrict__ Ks0, const char* __restrict__ Vt0,
    const char* __restrict__ Ks1, const char* __restrict__ Vt1,
    char* __restrict__ pwv0, char* __restrict__ pwv1,
    f16x8 qf0, f16x8 qf1, f32x4 (&acc)[4], float& m, float& l,
    bool diag1, int qrel, int l15, int g)
{
    f32x4 st[8];
    #pragma unroll
    for (int nt = 0; nt < 4; ++nt) {
        int kvl = (nt << 4) + l15;
        int off0 = kvl * 128 + (((g << 4)) ^ ((kvl & 7) << 4));
        int off1 = kvl * 128 + ((64 + (g << 4)) ^ ((kvl & 7) << 4));
        f16x8 ka0 = *(const f16x8*)&Ks0[off0];
        f16x8 ka1 = *(const f16x8*)&Ks0[off1];
        f32x4 z = (f32x4){0.f, 0.f, 0.f, 0.f};
        z = __builtin_amdgcn_mfma_f32_16x16x32_f16(ka0, qf0, z, 0, 0, 0);
        z = __builtin_amdgcn_mfma_f32_16x16x32_f16(ka1, qf1, z, 0, 0, 0);
        st[nt] = z;
        f16x8 kb0 = *(const f16x8*)&Ks1[off0];
        f16x8 kb1 = *(const f16x8*)&Ks1[off1];
        f32x4 z2 = (f32x4){0.f, 0.f, 0.f, 0.f};
        z2 = __builtin_amdgcn_mfma_f32_16x16x32_f16(kb0, qf0, z2, 0, 0, 0);
        z2 = __builtin_amdgcn_mfma_f32_16x16x32_f16(kb1, qf1, z2, 0, 0, 0);
        st[4 + nt] = z2;
    }
    if (diag1) {
        #pragma unroll
        for (int nt = 0; nt < 4; ++nt)
            #pragma unroll
            for (int r = 0; r < 4; ++r)
                if ((nt << 4) + (g << 2) + r > qrel) st[4 + nt][r] = -1e30f;
    }

    softmax_update<8>(st, acc, m, l, g);

    #pragma unroll
    for (int tile = 0; tile < 2; ++tile) {
        const char* Vt = tile ? Vt1 : Vt0;
        char* pwv = tile ? pwv1 : pwv0;
        f16x8 pa0, pa1;
        p_roundtrip(&st[tile << 2], pwv, l15, g, pa0, pa1);
        #pragma unroll
        for (int dn = 0; dn < 4; ++dn) {
            int d = (dn << 4) + l15;
            f16x8 vf0 = *(const f16x8*)&Vt[d * 128 + (((g << 4)) ^ ((d & 7) << 4))];
            f16x8 vf1 = *(const f16x8*)&Vt[d * 128 + ((64 + (g << 4)) ^ ((d & 7) << 4))];
            acc[dn] = __builtin_amdgcn_mfma_f32_16x16x32_f16(pa0, vf0, acc[dn], 0, 0, 0);
            acc[dn] = __builtin_amdgcn_mfma_f32_16x16x32_f16(pa1, vf1, acc[dn], 0, 0, 0);
        }
    }
}

// ---------------------------------------------------------------------------
// Flash attention, causal, fp16 MFMA. Paired q-tiles (qtA, 31-qtA), XCD-aware
// swizzle (FETCH 67->12.4 MB measured). R23: phase 1 also runs kv-tile PAIRS
// (2 tiles x 2 chains per barrier) -> ~9-13 barriers/block instead of 17.
// ---------------------------------------------------------------------------
__global__ __launch_bounds__(256, 4) void attn_mfma(
    const _Float16* __restrict__ Qh, const _Float16* __restrict__ Kh,
    const _Float16* __restrict__ VhT, _Float16* __restrict__ O)
{
    __shared__ char lds[80 * 1024];
#define KSLOT(s) (lds + ((s) << 13))
#define VSLOT(s) (lds + 32768 + ((s) << 13))

    // XCD swizzle: wg -> (qtA, bh). Bijective over 512 = 8 xcd x 4 bh x 16 qt.
    const int wg  = blockIdx.y * gridDim.x + blockIdx.x;
    const int idx = wg >> 3;                       // 0..63
    const int bh  = (wg & 7) * 4 + (idx >> 4);     // 4 heads per XCD slot
    const int qtA = idx & 15;                      // 0..15
    const int qtB = (SEQ / 64 - 1) - qtA;          // 31..16
    const int q0A = qtA << 6, q0B = qtB << 6;
    const int tid = threadIdx.x;
    const int w = tid >> 6, lane = tid & 63;
    const int l15 = lane & 15, g = lane >> 4;

    const _Float16* KhB = Kh  + (size_t)bh * SEQ * HEAD_D;
    const _Float16* VtB = VhT + (size_t)bh * HEAD_D * SEQ;
    const size_t headbase = (size_t)bh * SEQ * HEAD_D;

    const int qrowA = q0A + (w << 4) + l15;
    const int qrowB = q0B + (w << 4) + l15;
    f16x8 qfA0 = *(const f16x8*)&Qh[headbase + (size_t)qrowA * HEAD_D + (g << 3)];
    f16x8 qfA1 = *(const f16x8*)&Qh[headbase + (size_t)qrowA * HEAD_D + 32 + (g << 3)];
    f16x8 qfB0 = *(const f16x8*)&Qh[headbase + (size_t)qrowB * HEAD_D + (g << 3)];
    f16x8 qfB1 = *(const f16x8*)&Qh[headbase + (size_t)qrowB * HEAD_D + 32 + (g << 3)];

    f32x4 accA[4], accB[4];
    #pragma unroll
    for (int dn = 0; dn < 4; ++dn) {
        accA[dn] = (f32x4){0.f, 0.f, 0.f, 0.f};
        accB[dn] = (f32x4){0.f, 0.f, 0.f, 0.f};
    }
    float mA = -1e30f, lA = 0.f, mB = -1e30f, lB = 0.f;

    // ---- prologue: stage tiles 0 and 1 ----
    stage_kv_tile(KhB, VtB, 0,  KSLOT(0), VSLOT(0), w, lane);
    stage_kv_tile(KhB, VtB, 64, KSLOT(1), VSLOT(1), w, lane);
    __syncthreads();

    char* pwvA = lds + 65536 + (w << 11);
    char* pwvB = lds + 73728 + (w << 11);
    const int qrel = (w << 4) + l15;

    int kt = 0;
    // ---- phase 1 pairs: both chains, 2 kv tiles per barrier ----
    for (; kt + 1 <= qtA; kt += 2) {
        int pf0 = kt + 2, pf1 = kt + 3;
        if (pf0 <= qtB)
            stage_kv_tile(KhB, VtB, pf0 << 6, KSLOT(pf0 & 3), VSLOT(pf0 & 3), w, lane);
        if (pf1 <= qtB)
            stage_kv_tile(KhB, VtB, pf1 << 6, KSLOT(pf1 & 3), VSLOT(pf1 & 3), w, lane);
        attn_tile2_dual(KSLOT(kt & 3), VSLOT(kt & 3),
                        KSLOT((kt + 1) & 3), VSLOT((kt + 1) & 3),
                        pwvA, pwvB, qfA0, qfA1, qfB0, qfB1,
                        accA, accB, mA, lA, mB, lB,
                        (kt + 1) == qtA, qrel, l15, g);
        __syncthreads();
    }
    // ---- phase 1 tail: single kv tile, both chains (diag on A) ----
    if (kt == qtA) {
        int pf = kt + 2;
        if (pf <= qtB)
            stage_kv_tile(KhB, VtB, pf << 6, KSLOT(pf & 3), VSLOT(pf & 3), w, lane);
        attn_tile_dual(KSLOT(kt & 3), VSLOT(kt & 3), pwvA, pwvB,
                       qfA0, qfA1, qfB0, qfB1, accA, accB,
                       mA, lA, mB, lB, true, qrel, l15, g);
        __syncthreads();
        ++kt;
    }

    // ---- phase 2 head: single B tile at kt = qtA+1 (diag iff == qtB) ----
    {
        int pf = kt + 2;
        if (pf <= qtB)
            stage_kv_tile(KhB, VtB, pf << 6, KSLOT(pf & 3), VSLOT(pf & 3), w, lane);
        attn_tile(KSLOT(kt & 3), VSLOT(kt & 3), pwvB, qfB0, qfB1, accB, mB, lB,
                  kt == qtB, qrel, l15, g);
        __syncthreads();
        ++kt;
    }

    // ---- phase 2 pairs: single chain B, 2 kv tiles per barrier ----
    for (; kt < qtB; kt += 2) {
        int pf0 = kt + 2, pf1 = kt + 3;
        if (pf0 <= qtB)
            stage_kv_tile(KhB, VtB, pf0 << 6, KSLOT(pf0 & 3), VSLOT(pf0 & 3), w, lane);
        if (pf1 <= qtB)
            stage_kv_tile(KhB, VtB, pf1 << 6, KSLOT(pf1 & 3), VSLOT(pf1 & 3), w, lane);
        attn_tile2(KSLOT(kt & 3), VSLOT(kt & 3),
                   KSLOT((kt + 1) & 3), VSLOT((kt + 1) & 3),
                   pwvB, pwvA, qfB0, qfB1, accB, mB, lB,
                   (kt + 1) == qtB, qrel, l15, g);
        __syncthreads();
    }

    // ---- epilogue: deferred l reduction, normalize, store ----
    lA += __shfl_xor(lA, 16); lA += __shfl_xor(lA, 32);
    lB += __shfl_xor(lB, 16); lB += __shfl_xor(lB, 32);
    const int b = bh >> 4, h = bh & 15;
    const float rlA = 1.f / lA, rlB = 1.f / lB;
    #pragma unroll
    for (int r = 0; r < 4; ++r) {
        float invA = __shfl(rlA, (g << 2) + r);
        float invB = __shfl(rlB, (g << 2) + r);
        int tokA = (b << 11) + q0A + (w << 4) + (g << 2) + r;
        int tokB = (b << 11) + q0B + (w << 4) + (g << 2) + r;
        #pragma unroll
        for (int dn = 0; dn < 4; ++dn) {
            O[(size_t)tokA * EMB + (h << 6) + (dn << 4) + l15] =
                (_Float16)(accA[dn][r] * invA);
            O[(size_t)tokB * EMB + (h << 6) + (dn << 4) + l15] =
                (_Float16)(accB[dn][r] * invB);
        }
    }
#undef KSLOT
#undef VSLOT
}

// ---------------------------------------------------------------------------
extern "C" void kernel_launch(void* const* d_in, const int* in_sizes, int n_in,
                              void* d_out, int out_size, void* d_ws, size_t ws_size,
                              hipStream_t stream)
{
    const float* x  = (const float*)d_in[0];
    const float* Wq = (const float*)d_in[1];
    const float* Wk = (const float*)d_in[2];
    const float* Wv = (const float*)d_in[3];
    const float* Wo = (const float*)d_in[4];
    const float* bo = (const float*)d_in[5];
    float* out = (float*)d_out;

    const size_t ME = (size_t)MTOT * EMB;        // 4M elems
    const size_t WE = (size_t)EMB * EMB;         // 1M elems
    const size_t need = (5 * ME + 4 * WE) * sizeof(_Float16);
    if (ws_size < need) return;

    _Float16* xh  = (_Float16*)d_ws;
    _Float16* Wt  = xh + ME;
    _Float16* Wto = Wt + 3 * WE;
    _Float16* Qh  = Wto + WE;
    _Float16* Kh  = Qh + ME;
    _Float16* VhT = Kh + ME;   // V stored transposed [B,H,D,T] by the GEMM
    _Float16* Ow  = VhT + ME;

    prep_all<<<dim3(EMB / 32, EMB / 32, 5), 256, 0, stream>>>(
        x, Wq, Wk, Wv, Wo, xh, Wt, Wto);

    gemm_qkv<<<dim3(3 * EMB / 128, MTOT / 128), 256, 0, stream>>>(
        xh, Wt, Qh, Kh, VhT);

    attn_mfma<<<dim3(SEQ / 128, BATCH * NUM_HEADS), 256, 0, stream>>>(Qh, Kh, VhT, Ow);

    gemm_out<<<dim3(EMB / 64, MTOT / 128), 256, 0, stream>>>(
        Ow, Wto, out, bo);
}

// Round 24
// 111.054 us; speedup vs baseline: 1.0999x; 1.0999x over previous
//
#include <hip/hip_runtime.h>

typedef __attribute__((ext_vector_type(8))) _Float16 f16x8;
typedef __attribute__((ext_vector_type(4))) _Float16 f16x4;
typedef __attribute__((ext_vector_type(2))) _Float16 f16x2;
typedef __attribute__((ext_vector_type(2))) __fp16   fp16x2_raw;
typedef __attribute__((ext_vector_type(4))) float    f32x4;

#define NUM_HEADS 16
#define HEAD_D 64
#define EMB 1024
#define SEQ 2048
#define BATCH 2
#define MTOT (BATCH * SEQ) // 4096

// Q scale: 1/sqrt(64) * log2(e)  (softmax runs in exp2 domain)
#define QALPHA 0.18033688011112042f

__device__ __forceinline__ f16x2 cvt_pk_f16(float lo, float hi)
{
    fp16x2_raw r = __builtin_amdgcn_cvt_pkrtz(lo, hi);
    return __builtin_bit_cast(f16x2, r);
}

// Raw v_exp_f32 (2^x). Guarded: fall back to fast __expf if builtin absent.
#if defined(__has_builtin)
#if __has_builtin(__builtin_amdgcn_exp2f)
#define HAVE_EXP2 1
#endif
#endif
__device__ __forceinline__ float fast_exp2(float x)
{
#ifdef HAVE_EXP2
    return __builtin_amdgcn_exp2f(x);
#else
    return __expf(x * 0.6931471805599453f);
#endif
}

// ---------------------------------------------------------------------------
// global -> LDS direct staging (16 B per lane). LDS dest is wave-uniform
// base + lane*16 (HW behavior); fallback reg-stages to the same address.
// ---------------------------------------------------------------------------
#if defined(__has_builtin)
#if __has_builtin(__builtin_amdgcn_global_load_lds)
#define HAVE_GLOAD_LDS 1
#endif
#endif

__device__ __forceinline__ void stage16(const void* g, void* ldsWaveBase, int lane)
{
#ifdef HAVE_GLOAD_LDS
    __builtin_amdgcn_global_load_lds(
        (const __attribute__((address_space(1))) void*)g,
        (__attribute__((address_space(3))) void*)ldsWaveBase, 16, 0, 0);
    (void)lane;
#else
    *(f16x8*)((char*)ldsWaveBase + lane * 16) = *(const f16x8*)g;
#endif
}

// ---------------------------------------------------------------------------
// Fused prep: grid (32,32,5), 256 threads.
//  z=0..3 : transpose+cast W (z<3 -> Wt + z*WE, z=3 -> Wto)
//  z=4    : cast x -> xh (2 f16x8 chunks per thread)
// ---------------------------------------------------------------------------
__global__ __launch_bounds__(256) void prep_all(
    const float* __restrict__ x,
    const float* __restrict__ Wq, const float* __restrict__ Wk,
    const float* __restrict__ Wv, const float* __restrict__ Wo,
    _Float16* __restrict__ xh, _Float16* __restrict__ Wt,
    _Float16* __restrict__ Wto)
{
    const int z = blockIdx.z;
    if (z == 4) {
        int base = ((blockIdx.y * 32 + blockIdx.x) * 256 + threadIdx.x) * 2;
        #pragma unroll
        for (int t = 0; t < 2; ++t) {
            int i = base + t;
            float4 a = ((const float4*)x)[i * 2];
            float4 b = ((const float4*)x)[i * 2 + 1];
            f16x8 o;
            o[0] = (_Float16)a.x; o[1] = (_Float16)a.y;
            o[2] = (_Float16)a.z; o[3] = (_Float16)a.w;
            o[4] = (_Float16)b.x; o[5] = (_Float16)b.y;
            o[6] = (_Float16)b.z; o[7] = (_Float16)b.w;
            ((f16x8*)xh)[i] = o;
        }
        return;
    }
    const float* W = z == 0 ? Wq : (z == 1 ? Wk : (z == 2 ? Wv : Wo));
    _Float16* D = (z == 3) ? Wto : (Wt + (size_t)z * EMB * EMB);
    __shared__ float tile[32][33];
    const int tx = threadIdx.x & 31, ty = threadIdx.x >> 5; // (32, 8)
    const int n0 = blockIdx.x * 32, k0 = blockIdx.y * 32;
    #pragma unroll
    for (int j = 0; j < 4; ++j)
        tile[ty + j * 8][tx] = W[(size_t)(k0 + ty + j * 8) * EMB + n0 + tx];
    __syncthreads();
    #pragma unroll
    for (int j = 0; j < 4; ++j)
        D[(size_t)(n0 + ty + j * 8) * EMB + k0 + tx] =
            (_Float16)tile[tx][ty + j * 8];
}

// ---------------------------------------------------------------------------
// Fused QKV GEMM: [4096, 3072] = xh @ Wt^T. 128x128 tile, BK=32, 4 waves.
// R19 form (measured best). XCD swizzle col-major.
// Q,K written [B,H,T,D] (Q scaled by QALPHA); V written transposed [B,H,D,T].
// ---------------------------------------------------------------------------
__global__ __launch_bounds__(256) void gemm_qkv(
    const _Float16* __restrict__ A, const _Float16* __restrict__ Bt,
    _Float16* __restrict__ Qh, _Float16* __restrict__ Kh,
    _Float16* __restrict__ VhT)
{
    __shared__ __align__(16) _Float16 As[128 * 32]; // 8 KB
    __shared__ __align__(16) _Float16 Bs[128 * 32]; // 8 KB

    const int tid = threadIdx.x;
    const int w = tid >> 6, lane = tid & 63;
    const int l15 = lane & 15, g4 = lane >> 4;
    const int wm = w >> 1, wn = w & 1;

    // XCD-aware bijective remap (nwg = 768, 768 % 8 == 0)
    const int wg = blockIdx.y * gridDim.x + blockIdx.x;
    const int t  = (wg & 7) * 96 + (wg >> 3);
    const int bx = t >> 5, by = t & 31;     // col-major tile order
    const int row0 = by * 128, col0 = bx * 128;

    f32x4 acc[4][4];
    #pragma unroll
    for (int mt = 0; mt < 4; ++mt)
        #pragma unroll
        for (int nt = 0; nt < 4; ++nt)
            acc[mt][nt] = (f32x4){0.f, 0.f, 0.f, 0.f};

    for (int k0 = 0; k0 < EMB; k0 += 32) {
        __syncthreads();
        #pragma unroll
        for (int i = 0; i < 2; ++i) {
            int c = (i << 8) + tid;
            int row = c >> 2, u = c & 3;
            stage16(&A[(size_t)(row0 + row) * EMB + k0 + (u << 3)],
                    (char*)As + (i << 12) + (w << 10), lane);
            stage16(&Bt[(size_t)(col0 + row) * EMB + k0 + (u << 3)],
                    (char*)Bs + (i << 12) + (w << 10), lane);
        }
        __syncthreads();

        f16x8 af[4], bf[4];
        #pragma unroll
        for (int mt = 0; mt < 4; ++mt)
            af[mt] = *(const f16x8*)((const char*)As +
                     ((wm << 6) + (mt << 4) + l15) * 64 + (g4 << 4));
        #pragma unroll
        for (int nt = 0; nt < 4; ++nt)
            bf[nt] = *(const f16x8*)((const char*)Bs +
                     ((wn << 6) + (nt << 4) + l15) * 64 + (g4 << 4));
        #pragma unroll
        for (int mt = 0; mt < 4; ++mt)
            #pragma unroll
            for (int nt = 0; nt < 4; ++nt)
                acc[mt][nt] = __builtin_amdgcn_mfma_f32_16x16x32_f16(
                    af[mt], bf[nt], acc[mt][nt], 0, 0, 0);
    }

    // Epilogue. C/D: col = lane&15, row = 4*(lane>>4) + reg.
    #pragma unroll
    for (int mt = 0; mt < 4; ++mt) {
        int m = row0 + (wm << 6) + (mt << 4) + (g4 << 2);
        #pragma unroll
        for (int nt = 0; nt < 4; ++nt) {
            int gcol = col0 + (wn << 6) + (nt << 4) + l15;
            int proj = gcol >> 10, pc = gcol & 1023;
            int h = pc >> 6, d = pc & 63;
            int b = m >> 11, tt = m & 2047;
            int bh = b * NUM_HEADS + h;
            if (proj == 2) {
                f16x4 v4;
                v4[0] = (_Float16)acc[mt][nt][0];
                v4[1] = (_Float16)acc[mt][nt][1];
                v4[2] = (_Float16)acc[mt][nt][2];
                v4[3] = (_Float16)acc[mt][nt][3];
                *(f16x4*)&VhT[((size_t)bh * HEAD_D + d) * SEQ + tt] = v4;
            } else {
                _Float16* dst = proj == 0 ? Qh : Kh;
                float alpha = proj == 0 ? QALPHA : 1.0f;
                #pragma unroll
                for (int r = 0; r < 4; ++r)
                    dst[((size_t)bh * SEQ + tt + r) * HEAD_D + d] =
                        (_Float16)(acc[mt][nt][r] * alpha);
            }
        }
    }
}

// ---------------------------------------------------------------------------
// Output projection GEMM: [4096, 1024] fp32 + bias. 128x64 tile (512 blocks
// = 2/CU), BK=32 (R19 form), 4 waves, wave tile 64x32. XCD swizzle.
// ---------------------------------------------------------------------------
__global__ __launch_bounds__(256) void gemm_out(
    const _Float16* __restrict__ A, const _Float16* __restrict__ Bt,
    float* __restrict__ outf, const float* __restrict__ bias)
{
    __shared__ __align__(16) _Float16 As[128 * 32]; // 8 KB
    __shared__ __align__(16) _Float16 Bs[64 * 32];  // 4 KB

    const int tid = threadIdx.x;
    const int w = tid >> 6, lane = tid & 63;
    const int l15 = lane & 15, g4 = lane >> 4;
    const int wm = w >> 1, wn = w & 1;

    const int wg = blockIdx.y * gridDim.x + blockIdx.x;
    const int t  = (wg & 7) * 64 + (wg >> 3);
    const int bx = t >> 5, by = t & 31;
    const int row0 = by * 128, col0 = bx * 64;

    f32x4 acc[4][2];
    #pragma unroll
    for (int mt = 0; mt < 4; ++mt)
        #pragma unroll
        for (int nt = 0; nt < 2; ++nt)
            acc[mt][nt] = (f32x4){0.f, 0.f, 0.f, 0.f};

    for (int k0 = 0; k0 < EMB; k0 += 32) {
        __syncthreads();
        #pragma unroll
        for (int i = 0; i < 2; ++i) {
            int c = (i << 8) + tid;
            int row = c >> 2, u = c & 3;
            stage16(&A[(size_t)(row0 + row) * EMB + k0 + (u << 3)],
                    (char*)As + (i << 12) + (w << 10), lane);
        }
        {
            int row = tid >> 2, u = tid & 3; // 256 chunks: 64 rows x 4 units
            stage16(&Bt[(size_t)(col0 + row) * EMB + k0 + (u << 3)],
                    (char*)Bs + (w << 10), lane);
        }
        __syncthreads();

        f16x8 af[4], bf[2];
        #pragma unroll
        for (int mt = 0; mt < 4; ++mt)
            af[mt] = *(const f16x8*)((const char*)As +
                     ((wm << 6) + (mt << 4) + l15) * 64 + (g4 << 4));
        #pragma unroll
        for (int nt = 0; nt < 2; ++nt)
            bf[nt] = *(const f16x8*)((const char*)Bs +
                     ((wn << 5) + (nt << 4) + l15) * 64 + (g4 << 4));
        #pragma unroll
        for (int mt = 0; mt < 4; ++mt)
            #pragma unroll
            for (int nt = 0; nt < 2; ++nt)
                acc[mt][nt] = __builtin_amdgcn_mfma_f32_16x16x32_f16(
                    af[mt], bf[nt], acc[mt][nt], 0, 0, 0);
    }

    #pragma unroll
    for (int mt = 0; mt < 4; ++mt) {
        int m = row0 + (wm << 6) + (mt << 4) + (g4 << 2);
        #pragma unroll
        for (int nt = 0; nt < 2; ++nt) {
            int gcol = col0 + (wn << 5) + (nt << 4) + l15;
            float bz = bias[gcol];
            #pragma unroll
            for (int r = 0; r < 4; ++r)
                outf[(size_t)(m + r) * EMB + gcol] = acc[mt][nt][r] + bz;
        }
    }
}

// ---------------------------------------------------------------------------
// Stage one 64-kv K tile + V^T tile into LDS via global_load_lds with
// pre-swizzled global source (LDS dest linear; chunk (row,u) holds global
// (row, u^(row&7)) -> read formulas identical to the verified K-frag path).
// ---------------------------------------------------------------------------
__device__ __forceinline__ void stage_kv_tile(
    const _Float16* __restrict__ KhB, const _Float16* __restrict__ VtB,
    int kv0, char* __restrict__ KsBuf, char* __restrict__ VtBuf,
    int w, int lane)
{
    #pragma unroll
    for (int i = 0; i < 2; ++i) {
        int c = (i << 8) + (w << 6) + lane;
        int row = c >> 3, u = c & 7;
        int us = u ^ (row & 7);
        stage16(&KhB[(size_t)(kv0 + row) * HEAD_D + (us << 3)],
                KsBuf + (i << 12) + (w << 10), lane);
        stage16(&VtB[(size_t)row * SEQ + kv0 + (us << 3)],
                VtBuf + (i << 12) + (w << 10), lane);
    }
}

// ---------------------------------------------------------------------------
// Single 64q x 64kv attention tile step (verified R15 form): S^T = K Q^T,
// shuffle-free defer-max softmax, per-lane partial l, P roundtrip, PV.
// ---------------------------------------------------------------------------
__device__ __forceinline__ void attn_tile(
    const char* __restrict__ KsC, const char* __restrict__ VtC,
    char* __restrict__ pwv,
    f16x8 qf0, f16x8 qf1, f32x4 (&acc)[4], float& m, float& l,
    bool diag, int qrel, int l15, int g)
{
    f32x4 st[4];
    #pragma unroll
    for (int nt = 0; nt < 4; ++nt) {
        int kvl = (nt << 4) + l15;
        f16x8 kf0 = *(const f16x8*)&KsC[kvl * 128 + (((g << 4)) ^ ((kvl & 7) << 4))];
        f16x8 kf1 = *(const f16x8*)&KsC[kvl * 128 + ((64 + (g << 4)) ^ ((kvl & 7) << 4))];
        f32x4 z = (f32x4){0.f, 0.f, 0.f, 0.f};
        z = __builtin_amdgcn_mfma_f32_16x16x32_f16(kf0, qf0, z, 0, 0, 0);
        z = __builtin_amdgcn_mfma_f32_16x16x32_f16(kf1, qf1, z, 0, 0, 0);
        st[nt] = z;
    }
    if (diag) {
        #pragma unroll
        for (int nt = 0; nt < 4; ++nt)
            #pragma unroll
            for (int r = 0; r < 4; ++r)
                if ((nt << 4) + (g << 2) + r > qrel) st[nt][r] = -1e30f;
    }

    float mx;
    {
        float a0 = fmaxf(fmaxf(st[0][0], st[0][1]), fmaxf(st[0][2], st[0][3]));
        float a1 = fmaxf(fmaxf(st[1][0], st[1][1]), fmaxf(st[1][2], st[1][3]));
        float a2 = fmaxf(fmaxf(st[2][0], st[2][1]), fmaxf(st[2][2], st[2][3]));
        float a3 = fmaxf(fmaxf(st[3][0], st[3][1]), fmaxf(st[3][2], st[3][3]));
        mx = fmaxf(fmaxf(a0, a1), fmaxf(a2, a3));
    }

    if (!__all(mx - m <= 8.0f)) {
        float mxr = fmaxf(mx, __shfl_xor(mx, 16));
        mxr = fmaxf(mxr, __shfl_xor(mxr, 32));
        float nm = fmaxf(m, mxr);
        float sc = fast_exp2(m - nm);   // row-uniform
        m = nm;
        l *= sc;
        #pragma unroll
        for (int r = 0; r < 4; ++r) {
            float scr = __shfl(sc, (g << 2) + r);
            acc[0][r] *= scr; acc[1][r] *= scr;
            acc[2][r] *= scr; acc[3][r] *= scr;
        }
    }

    float ps = 0.f;
    #pragma unroll
    for (int nt = 0; nt < 4; ++nt)
        #pragma unroll
        for (int r = 0; r < 4; ++r) {
            float p = fast_exp2(st[nt][r] - m);
            st[nt][r] = p;
            ps += p;
        }
    l += ps;

    #pragma unroll
    for (int nt = 0; nt < 4; ++nt)
        #pragma unroll
        for (int rr = 0; rr < 2; ++rr) {
            int kvb = (nt << 4) + (g << 2) + (rr << 1);
            f16x2 pv = cvt_pk_f16(st[nt][rr * 2], st[nt][rr * 2 + 1]);
            *(f16x2*)&pwv[l15 * 128 + ((kvb << 1) ^ ((l15 & 7) << 4))] = pv;
        }
    f16x8 pa0 = *(const f16x8*)&pwv[l15 * 128 + (((g << 4)) ^ ((l15 & 7) << 4))];
    f16x8 pa1 = *(const f16x8*)&pwv[l15 * 128 + ((64 + (g << 4)) ^ ((l15 & 7) << 4))];

    #pragma unroll
    for (int dn = 0; dn < 4; ++dn) {
        int d = (dn << 4) + l15;
        f16x8 vf0 = *(const f16x8*)&VtC[d * 128 + (((g << 4)) ^ ((d & 7) << 4))];
        f16x8 vf1 = *(const f16x8*)&VtC[d * 128 + ((64 + (g << 4)) ^ ((d & 7) << 4))];
        acc[dn] = __builtin_amdgcn_mfma_f32_16x16x32_f16(pa0, vf0, acc[dn], 0, 0, 0);
        acc[dn] = __builtin_amdgcn_mfma_f32_16x16x32_f16(pa1, vf1, acc[dn], 0, 0, 0);
    }
}

// ---------------------------------------------------------------------------
// Dual-chain single-kv step (R22, measured best): shared K/V fragments feed
// both chains' MFMAs. diag applies to A only.
// ---------------------------------------------------------------------------
__device__ __forceinline__ void attn_tile_dual(
    const char* __restrict__ KsC, const char* __restrict__ VtC,
    char* __restrict__ pwvA, char* __restrict__ pwvB,
    f16x8 qfA0, f16x8 qfA1, f16x8 qfB0, f16x8 qfB1,
    f32x4 (&accA)[4], f32x4 (&accB)[4],
    float& mA, float& lA, float& mB, float& lB,
    bool diagA, int qrel, int l15, int g)
{
    f32x4 sA[4], sB[4];
    #pragma unroll
    for (int nt = 0; nt < 4; ++nt) {
        int kvl = (nt << 4) + l15;
        f16x8 kf0 = *(const f16x8*)&KsC[kvl * 128 + (((g << 4)) ^ ((kvl & 7) << 4))];
        f16x8 kf1 = *(const f16x8*)&KsC[kvl * 128 + ((64 + (g << 4)) ^ ((kvl & 7) << 4))];
        f32x4 zA = (f32x4){0.f, 0.f, 0.f, 0.f};
        zA = __builtin_amdgcn_mfma_f32_16x16x32_f16(kf0, qfA0, zA, 0, 0, 0);
        zA = __builtin_amdgcn_mfma_f32_16x16x32_f16(kf1, qfA1, zA, 0, 0, 0);
        sA[nt] = zA;
        f32x4 zB = (f32x4){0.f, 0.f, 0.f, 0.f};
        zB = __builtin_amdgcn_mfma_f32_16x16x32_f16(kf0, qfB0, zB, 0, 0, 0);
        zB = __builtin_amdgcn_mfma_f32_16x16x32_f16(kf1, qfB1, zB, 0, 0, 0);
        sB[nt] = zB;
    }
    if (diagA) {
        #pragma unroll
        for (int nt = 0; nt < 4; ++nt)
            #pragma unroll
            for (int r = 0; r < 4; ++r)
                if ((nt << 4) + (g << 2) + r > qrel) sA[nt][r] = -1e30f;
    }

    // softmax A
    {
        float a0 = fmaxf(fmaxf(sA[0][0], sA[0][1]), fmaxf(sA[0][2], sA[0][3]));
        float a1 = fmaxf(fmaxf(sA[1][0], sA[1][1]), fmaxf(sA[1][2], sA[1][3]));
        float a2 = fmaxf(fmaxf(sA[2][0], sA[2][1]), fmaxf(sA[2][2], sA[2][3]));
        float a3 = fmaxf(fmaxf(sA[3][0], sA[3][1]), fmaxf(sA[3][2], sA[3][3]));
        float mx = fmaxf(fmaxf(a0, a1), fmaxf(a2, a3));
        if (!__all(mx - mA <= 8.0f)) {
            float mxr = fmaxf(mx, __shfl_xor(mx, 16));
            mxr = fmaxf(mxr, __shfl_xor(mxr, 32));
            float nm = fmaxf(mA, mxr);
            float sc = fast_exp2(mA - nm);
            mA = nm;
            lA *= sc;
            #pragma unroll
            for (int r = 0; r < 4; ++r) {
                float scr = __shfl(sc, (g << 2) + r);
                accA[0][r] *= scr; accA[1][r] *= scr;
                accA[2][r] *= scr; accA[3][r] *= scr;
            }
        }
        float ps = 0.f;
        #pragma unroll
        for (int nt = 0; nt < 4; ++nt)
            #pragma unroll
            for (int r = 0; r < 4; ++r) {
                float p = fast_exp2(sA[nt][r] - mA);
                sA[nt][r] = p;
                ps += p;
            }
        lA += ps;
    }
    // softmax B
    {
        float a0 = fmaxf(fmaxf(sB[0][0], sB[0][1]), fmaxf(sB[0][2], sB[0][3]));
        float a1 = fmaxf(fmaxf(sB[1][0], sB[1][1]), fmaxf(sB[1][2], sB[1][3]));
        float a2 = fmaxf(fmaxf(sB[2][0], sB[2][1]), fmaxf(sB[2][2], sB[2][3]));
        float a3 = fmaxf(fmaxf(sB[3][0], sB[3][1]), fmaxf(sB[3][2], sB[3][3]));
        float mx = fmaxf(fmaxf(a0, a1), fmaxf(a2, a3));
        if (!__all(mx - mB <= 8.0f)) {
            float mxr = fmaxf(mx, __shfl_xor(mx, 16));
            mxr = fmaxf(mxr, __shfl_xor(mxr, 32));
            float nm = fmaxf(mB, mxr);
            float sc = fast_exp2(mB - nm);
            mB = nm;
            lB *= sc;
            #pragma unroll
            for (int r = 0; r < 4; ++r) {
                float scr = __shfl(sc, (g << 2) + r);
                accB[0][r] *= scr; accB[1][r] *= scr;
                accB[2][r] *= scr; accB[3][r] *= scr;
            }
        }
        float ps = 0.f;
        #pragma unroll
        for (int nt = 0; nt < 4; ++nt)
            #pragma unroll
            for (int r = 0; r < 4; ++r) {
                float p = fast_exp2(sB[nt][r] - mB);
                sB[nt][r] = p;
                ps += p;
            }
        lB += ps;
    }

    // P writes for both chains (independent regions)
    #pragma unroll
    for (int nt = 0; nt < 4; ++nt)
        #pragma unroll
        for (int rr = 0; rr < 2; ++rr) {
            int kvb = (nt << 4) + (g << 2) + (rr << 1);
            int off = l15 * 128 + ((kvb << 1) ^ ((l15 & 7) << 4));
            *(f16x2*)&pwvA[off] = cvt_pk_f16(sA[nt][rr * 2], sA[nt][rr * 2 + 1]);
            *(f16x2*)&pwvB[off] = cvt_pk_f16(sB[nt][rr * 2], sB[nt][rr * 2 + 1]);
        }
    int poff0 = l15 * 128 + (((g << 4)) ^ ((l15 & 7) << 4));
    int poff1 = l15 * 128 + ((64 + (g << 4)) ^ ((l15 & 7) << 4));
    f16x8 paA0 = *(const f16x8*)&pwvA[poff0];
    f16x8 paA1 = *(const f16x8*)&pwvA[poff1];
    f16x8 paB0 = *(const f16x8*)&pwvB[poff0];
    f16x8 paB1 = *(const f16x8*)&pwvB[poff1];

    // PV: shared V fragments feed both chains
    #pragma unroll
    for (int dn = 0; dn < 4; ++dn) {
        int d = (dn << 4) + l15;
        f16x8 vf0 = *(const f16x8*)&VtC[d * 128 + (((g << 4)) ^ ((d & 7) << 4))];
        f16x8 vf1 = *(const f16x8*)&VtC[d * 128 + ((64 + (g << 4)) ^ ((d & 7) << 4))];
        accA[dn] = __builtin_amdgcn_mfma_f32_16x16x32_f16(paA0, vf0, accA[dn], 0, 0, 0);
        accA[dn] = __builtin_amdgcn_mfma_f32_16x16x32_f16(paA1, vf1, accA[dn], 0, 0, 0);
        accB[dn] = __builtin_amdgcn_mfma_f32_16x16x32_f16(paB0, vf0, accB[dn], 0, 0, 0);
        accB[dn] = __builtin_amdgcn_mfma_f32_16x16x32_f16(paB1, vf1, accB[dn], 0, 0, 0);
    }
}

// ---------------------------------------------------------------------------
// Dual-kv tile step for one chain: QK over BOTH tiles, ONE merged softmax
// pass, two P->PV steps with separate P regions. diag only on SECOND tile.
// ---------------------------------------------------------------------------
__device__ __forceinline__ void attn_tile2(
    const char* __restrict__ Ks0, const char* __restrict__ Vt0,
    const char* __restrict__ Ks1, const char* __restrict__ Vt1,
    char* __restrict__ pwv0, char* __restrict__ pwv1,
    f16x8 qf0, f16x8 qf1, f32x4 (&acc)[4], float& m, float& l,
    bool diag1, int qrel, int l15, int g)
{
    f32x4 st[8];
    #pragma unroll
    for (int nt = 0; nt < 4; ++nt) {
        int kvl = (nt << 4) + l15;
        int off0 = kvl * 128 + (((g << 4)) ^ ((kvl & 7) << 4));
        int off1 = kvl * 128 + ((64 + (g << 4)) ^ ((kvl & 7) << 4));
        f16x8 ka0 = *(const f16x8*)&Ks0[off0];
        f16x8 ka1 = *(const f16x8*)&Ks0[off1];
        f32x4 z = (f32x4){0.f, 0.f, 0.f, 0.f};
        z = __builtin_amdgcn_mfma_f32_16x16x32_f16(ka0, qf0, z, 0, 0, 0);
        z = __builtin_amdgcn_mfma_f32_16x16x32_f16(ka1, qf1, z, 0, 0, 0);
        st[nt] = z;
        f16x8 kb0 = *(const f16x8*)&Ks1[off0];
        f16x8 kb1 = *(const f16x8*)&Ks1[off1];
        f32x4 z2 = (f32x4){0.f, 0.f, 0.f, 0.f};
        z2 = __builtin_amdgcn_mfma_f32_16x16x32_f16(kb0, qf0, z2, 0, 0, 0);
        z2 = __builtin_amdgcn_mfma_f32_16x16x32_f16(kb1, qf1, z2, 0, 0, 0);
        st[4 + nt] = z2;
    }
    if (diag1) {
        #pragma unroll
        for (int nt = 0; nt < 4; ++nt)
            #pragma unroll
            for (int r = 0; r < 4; ++r)
                if ((nt << 4) + (g << 2) + r > qrel) st[4 + nt][r] = -1e30f;
    }

    float mx;
    {
        float a = -1e30f;
        #pragma unroll
        for (int i = 0; i < 8; ++i)
            a = fmaxf(a, fmaxf(fmaxf(st[i][0], st[i][1]),
                               fmaxf(st[i][2], st[i][3])));
        mx = a;
    }

    if (!__all(mx - m <= 8.0f)) {
        float mxr = fmaxf(mx, __shfl_xor(mx, 16));
        mxr = fmaxf(mxr, __shfl_xor(mxr, 32));
        float nm = fmaxf(m, mxr);
        float sc = fast_exp2(m - nm);
        m = nm;
        l *= sc;
        #pragma unroll
        for (int r = 0; r < 4; ++r) {
            float scr = __shfl(sc, (g << 2) + r);
            acc[0][r] *= scr; acc[1][r] *= scr;
            acc[2][r] *= scr; acc[3][r] *= scr;
        }
    }

    float ps = 0.f;
    #pragma unroll
    for (int i = 0; i < 8; ++i)
        #pragma unroll
        for (int r = 0; r < 4; ++r) {
            float p = fast_exp2(st[i][r] - m);
            st[i][r] = p;
            ps += p;
        }
    l += ps;

    // PV tile 0 -> pwv0, tile 1 -> pwv1 (independent regions)
    #pragma unroll
    for (int tile = 0; tile < 2; ++tile) {
        const f32x4* s4 = &st[tile << 2];
        const char* Vt = tile ? Vt1 : Vt0;
        char* pwv = tile ? pwv1 : pwv0;
        #pragma unroll
        for (int nt = 0; nt < 4; ++nt)
            #pragma unroll
            for (int rr = 0; rr < 2; ++rr) {
                int kvb = (nt << 4) + (g << 2) + (rr << 1);
                f16x2 pv = cvt_pk_f16(s4[nt][rr * 2], s4[nt][rr * 2 + 1]);
                *(f16x2*)&pwv[l15 * 128 + ((kvb << 1) ^ ((l15 & 7) << 4))] = pv;
            }
        f16x8 pa0 = *(const f16x8*)&pwv[l15 * 128 + (((g << 4)) ^ ((l15 & 7) << 4))];
        f16x8 pa1 = *(const f16x8*)&pwv[l15 * 128 + ((64 + (g << 4)) ^ ((l15 & 7) << 4))];
        #pragma unroll
        for (int dn = 0; dn < 4; ++dn) {
            int d = (dn << 4) + l15;
            f16x8 vf0 = *(const f16x8*)&Vt[d * 128 + (((g << 4)) ^ ((d & 7) << 4))];
            f16x8 vf1 = *(const f16x8*)&Vt[d * 128 + ((64 + (g << 4)) ^ ((d & 7) << 4))];
            acc[dn] = __builtin_amdgcn_mfma_f32_16x16x32_f16(pa0, vf0, acc[dn], 0, 0, 0);
            acc[dn] = __builtin_amdgcn_mfma_f32_16x16x32_f16(pa1, vf1, acc[dn], 0, 0, 0);
        }
    }
}

// ---------------------------------------------------------------------------
// Flash attention, causal, fp16 MFMA. Paired q-tiles (qtA, 31-qtA) with
// UNIFORM 17 iterations per block. XCD-aware swizzle (each XCD owns 4 heads,
// K/V L2-resident: FETCH 67->12.4 MB measured). Phase 1 uses the shared-
// fragment dual-chain step.
// ---------------------------------------------------------------------------
__global__ __launch_bounds__(256, 4) void attn_mfma(
    const _Float16* __restrict__ Qh, const _Float16* __restrict__ Kh,
    const _Float16* __restrict__ VhT, _Float16* __restrict__ O)
{
    __shared__ char lds[80 * 1024];
#define KSLOT(s) (lds + ((s) << 13))
#define VSLOT(s) (lds + 32768 + ((s) << 13))

    // XCD swizzle: wg -> (qtA, bh). Bijective over 512 = 8 xcd x 4 bh x 16 qt.
    const int wg  = blockIdx.y * gridDim.x + blockIdx.x;
    const int idx = wg >> 3;                       // 0..63
    const int bh  = (wg & 7) * 4 + (idx >> 4);     // 4 heads per XCD slot
    const int qtA = idx & 15;                      // 0..15
    const int qtB = (SEQ / 64 - 1) - qtA;          // 31..16
    const int q0A = qtA << 6, q0B = qtB << 6;
    const int tid = threadIdx.x;
    const int w = tid >> 6, lane = tid & 63;
    const int l15 = lane & 15, g = lane >> 4;

    const _Float16* KhB = Kh  + (size_t)bh * SEQ * HEAD_D;
    const _Float16* VtB = VhT + (size_t)bh * HEAD_D * SEQ;
    const size_t headbase = (size_t)bh * SEQ * HEAD_D;

    const int qrowA = q0A + (w << 4) + l15;
    const int qrowB = q0B + (w << 4) + l15;
    f16x8 qfA0 = *(const f16x8*)&Qh[headbase + (size_t)qrowA * HEAD_D + (g << 3)];
    f16x8 qfA1 = *(const f16x8*)&Qh[headbase + (size_t)qrowA * HEAD_D + 32 + (g << 3)];
    f16x8 qfB0 = *(const f16x8*)&Qh[headbase + (size_t)qrowB * HEAD_D + (g << 3)];
    f16x8 qfB1 = *(const f16x8*)&Qh[headbase + (size_t)qrowB * HEAD_D + 32 + (g << 3)];

    f32x4 accA[4], accB[4];
    #pragma unroll
    for (int dn = 0; dn < 4; ++dn) {
        accA[dn] = (f32x4){0.f, 0.f, 0.f, 0.f};
        accB[dn] = (f32x4){0.f, 0.f, 0.f, 0.f};
    }
    float mA = -1e30f, lA = 0.f, mB = -1e30f, lB = 0.f;

    // ---- prologue: stage tiles 0 and 1 ----
    stage_kv_tile(KhB, VtB, 0,  KSLOT(0), VSLOT(0), w, lane);
    stage_kv_tile(KhB, VtB, 64, KSLOT(1), VSLOT(1), w, lane);
    __syncthreads();

    char* pwvA = lds + 65536 + (w << 11);
    char* pwvB = lds + 73728 + (w << 11);
    const int qrel = (w << 4) + l15;

    // ---- phase 1: kt = 0..qtA, shared kv, dual chains (shared K/V frags) ----
    for (int kt = 0; kt <= qtA; ++kt) {
        int pf = kt + 2;
        if (pf <= qtB)
            stage_kv_tile(KhB, VtB, pf << 6, KSLOT(pf & 3), VSLOT(pf & 3), w, lane);
        attn_tile_dual(KSLOT(kt & 3), VSLOT(kt & 3), pwvA, pwvB,
                       qfA0, qfA1, qfB0, qfB1, accA, accB,
                       mA, lA, mB, lB, kt == qtA, qrel, l15, g);
        __syncthreads();
    }

    // ---- phase 2 head: single B tile at kt = qtA+1 (diag iff == qtB) ----
    {
        int kt = qtA + 1;
        int pf = kt + 2;
        if (pf <= qtB)
            stage_kv_tile(KhB, VtB, pf << 6, KSLOT(pf & 3), VSLOT(pf & 3), w, lane);
        attn_tile(KSLOT(kt & 3), VSLOT(kt & 3), pwvB, qfB0, qfB1, accB, mB, lB,
                  kt == qtB, qrel, l15, g);
        __syncthreads();
    }

    // ---- phase 2 pairs: kt = qtA+2, step 2, through qtB ----
    for (int kt = qtA + 2; kt < qtB; kt += 2) {
        int pf0 = kt + 2, pf1 = kt + 3;
        if (pf0 <= qtB)
            stage_kv_tile(KhB, VtB, pf0 << 6, KSLOT(pf0 & 3), VSLOT(pf0 & 3), w, lane);
        if (pf1 <= qtB)
            stage_kv_tile(KhB, VtB, pf1 << 6, KSLOT(pf1 & 3), VSLOT(pf1 & 3), w, lane);
        attn_tile2(KSLOT(kt & 3), VSLOT(kt & 3),
                   KSLOT((kt + 1) & 3), VSLOT((kt + 1) & 3),
                   pwvB, pwvA, qfB0, qfB1, accB, mB, lB,
                   (kt + 1) == qtB, qrel, l15, g);
        __syncthreads();
    }

    // ---- epilogue: deferred l reduction, normalize, store ----
    lA += __shfl_xor(lA, 16); lA += __shfl_xor(lA, 32);
    lB += __shfl_xor(lB, 16); lB += __shfl_xor(lB, 32);
    const int b = bh >> 4, h = bh & 15;
    const float rlA = 1.f / lA, rlB = 1.f / lB;
    #pragma unroll
    for (int r = 0; r < 4; ++r) {
        float invA = __shfl(rlA, (g << 2) + r);
        float invB = __shfl(rlB, (g << 2) + r);
        int tokA = (b << 11) + q0A + (w << 4) + (g << 2) + r;
        int tokB = (b << 11) + q0B + (w << 4) + (g << 2) + r;
        #pragma unroll
        for (int dn = 0; dn < 4; ++dn) {
            O[(size_t)tokA * EMB + (h << 6) + (dn << 4) + l15] =
                (_Float16)(accA[dn][r] * invA);
            O[(size_t)tokB * EMB + (h << 6) + (dn << 4) + l15] =
                (_Float16)(accB[dn][r] * invB);
        }
    }
#undef KSLOT
#undef VSLOT
}

// ---------------------------------------------------------------------------
extern "C" void kernel_launch(void* const* d_in, const int* in_sizes, int n_in,
                              void* d_out, int out_size, void* d_ws, size_t ws_size,
                              hipStream_t stream)
{
    const float* x  = (const float*)d_in[0];
    const float* Wq = (const float*)d_in[1];
    const float* Wk = (const float*)d_in[2];
    const float* Wv = (const float*)d_in[3];
    const float* Wo = (const float*)d_in[4];
    const float* bo = (const float*)d_in[5];
    float* out = (float*)d_out;

    const size_t ME = (size_t)MTOT * EMB;        // 4M elems
    const size_t WE = (size_t)EMB * EMB;         // 1M elems
    const size_t need = (5 * ME + 4 * WE) * sizeof(_Float16);
    if (ws_size < need) return;

    _Float16* xh  = (_Float16*)d_ws;
    _Float16* Wt  = xh + ME;
    _Float16* Wto = Wt + 3 * WE;
    _Float16* Qh  = Wto + WE;
    _Float16* Kh  = Qh + ME;
    _Float16* VhT = Kh + ME;   // V stored transposed [B,H,D,T] by the GEMM
    _Float16* Ow  = VhT + ME;

    prep_all<<<dim3(EMB / 32, EMB / 32, 5), 256, 0, stream>>>(
        x, Wq, Wk, Wv, Wo, xh, Wt, Wto);

    gemm_qkv<<<dim3(3 * EMB / 128, MTOT / 128), 256, 0, stream>>>(
        xh, Wt, Qh, Kh, VhT);

    attn_mfma<<<dim3(SEQ / 128, BATCH * NUM_HEADS), 256, 0, stream>>>(Qh, Kh, VhT, Ow);

    gemm_out<<<dim3(EMB / 64, MTOT / 128), 256, 0, stream>>>(
        Ow, Wto, out, bo);
}

// Round 25
// 110.549 us; speedup vs baseline: 1.1049x; 1.0046x over previous
//
#include <hip/hip_runtime.h>

typedef __attribute__((ext_vector_type(8))) _Float16 f16x8;
typedef __attribute__((ext_vector_type(4))) _Float16 f16x4;
typedef __attribute__((ext_vector_type(2))) _Float16 f16x2;
typedef __attribute__((ext_vector_type(2))) __fp16   fp16x2_raw;
typedef __attribute__((ext_vector_type(4))) float    f32x4;

#define NUM_HEADS 16
#define HEAD_D 64
#define EMB 1024
#define SEQ 2048
#define BATCH 2
#define MTOT (BATCH * SEQ) // 4096

// Q scale: 1/sqrt(64) * log2(e)  (softmax runs in exp2 domain)
#define QALPHA 0.18033688011112042f

__device__ __forceinline__ f16x2 cvt_pk_f16(float lo, float hi)
{
    fp16x2_raw r = __builtin_amdgcn_cvt_pkrtz(lo, hi);
    return __builtin_bit_cast(f16x2, r);
}

// Raw v_exp_f32 (2^x). Guarded: fall back to fast __expf if builtin absent.
#if defined(__has_builtin)
#if __has_builtin(__builtin_amdgcn_exp2f)
#define HAVE_EXP2 1
#endif
#endif
__device__ __forceinline__ float fast_exp2(float x)
{
#ifdef HAVE_EXP2
    return __builtin_amdgcn_exp2f(x);
#else
    return __expf(x * 0.6931471805599453f);
#endif
}

// ---------------------------------------------------------------------------
// global -> LDS direct staging (16 B per lane). LDS dest is wave-uniform
// base + lane*16 (HW behavior); fallback reg-stages to the same address.
// ---------------------------------------------------------------------------
#if defined(__has_builtin)
#if __has_builtin(__builtin_amdgcn_global_load_lds)
#define HAVE_GLOAD_LDS 1
#endif
#endif

__device__ __forceinline__ void stage16(const void* g, void* ldsWaveBase, int lane)
{
#ifdef HAVE_GLOAD_LDS
    __builtin_amdgcn_global_load_lds(
        (const __attribute__((address_space(1))) void*)g,
        (__attribute__((address_space(3))) void*)ldsWaveBase, 16, 0, 0);
    (void)lane;
#else
    *(f16x8*)((char*)ldsWaveBase + lane * 16) = *(const f16x8*)g;
#endif
}

// ---------------------------------------------------------------------------
// Fused prep: grid (32,32,5), 256 threads.
//  z=0..3 : transpose+cast W (z<3 -> Wt + z*WE, z=3 -> Wto)
//  z=4    : cast x -> xh (2 f16x8 chunks per thread)
// ---------------------------------------------------------------------------
__global__ __launch_bounds__(256) void prep_all(
    const float* __restrict__ x,
    const float* __restrict__ Wq, const float* __restrict__ Wk,
    const float* __restrict__ Wv, const float* __restrict__ Wo,
    _Float16* __restrict__ xh, _Float16* __restrict__ Wt,
    _Float16* __restrict__ Wto)
{
    const int z = blockIdx.z;
    if (z == 4) {
        int base = ((blockIdx.y * 32 + blockIdx.x) * 256 + threadIdx.x) * 2;
        #pragma unroll
        for (int t = 0; t < 2; ++t) {
            int i = base + t;
            float4 a = ((const float4*)x)[i * 2];
            float4 b = ((const float4*)x)[i * 2 + 1];
            f16x8 o;
            o[0] = (_Float16)a.x; o[1] = (_Float16)a.y;
            o[2] = (_Float16)a.z; o[3] = (_Float16)a.w;
            o[4] = (_Float16)b.x; o[5] = (_Float16)b.y;
            o[6] = (_Float16)b.z; o[7] = (_Float16)b.w;
            ((f16x8*)xh)[i] = o;
        }
        return;
    }
    const float* W = z == 0 ? Wq : (z == 1 ? Wk : (z == 2 ? Wv : Wo));
    _Float16* D = (z == 3) ? Wto : (Wt + (size_t)z * EMB * EMB);
    __shared__ float tile[32][33];
    const int tx = threadIdx.x & 31, ty = threadIdx.x >> 5; // (32, 8)
    const int n0 = blockIdx.x * 32, k0 = blockIdx.y * 32;
    #pragma unroll
    for (int j = 0; j < 4; ++j)
        tile[ty + j * 8][tx] = W[(size_t)(k0 + ty + j * 8) * EMB + n0 + tx];
    __syncthreads();
    #pragma unroll
    for (int j = 0; j < 4; ++j)
        D[(size_t)(n0 + ty + j * 8) * EMB + k0 + tx] =
            (_Float16)tile[tx][ty + j * 8];
}

// ---------------------------------------------------------------------------
// Fused QKV GEMM: [4096, 3072] = xh @ Wt^T. 128x128 tile, BK=32, 4 waves.
// R19 form (measured best). XCD swizzle col-major.
// Q,K written [B,H,T,D] (Q scaled by QALPHA); V written transposed [B,H,D,T].
// ---------------------------------------------------------------------------
__global__ __launch_bounds__(256) void gemm_qkv(
    const _Float16* __restrict__ A, const _Float16* __restrict__ Bt,
    _Float16* __restrict__ Qh, _Float16* __restrict__ Kh,
    _Float16* __restrict__ VhT)
{
    __shared__ __align__(16) _Float16 As[128 * 32]; // 8 KB
    __shared__ __align__(16) _Float16 Bs[128 * 32]; // 8 KB

    const int tid = threadIdx.x;
    const int w = tid >> 6, lane = tid & 63;
    const int l15 = lane & 15, g4 = lane >> 4;
    const int wm = w >> 1, wn = w & 1;

    // XCD-aware bijective remap (nwg = 768, 768 % 8 == 0)
    const int wg = blockIdx.y * gridDim.x + blockIdx.x;
    const int t  = (wg & 7) * 96 + (wg >> 3);
    const int bx = t >> 5, by = t & 31;     // col-major tile order
    const int row0 = by * 128, col0 = bx * 128;

    f32x4 acc[4][4];
    #pragma unroll
    for (int mt = 0; mt < 4; ++mt)
        #pragma unroll
        for (int nt = 0; nt < 4; ++nt)
            acc[mt][nt] = (f32x4){0.f, 0.f, 0.f, 0.f};

    for (int k0 = 0; k0 < EMB; k0 += 32) {
        __syncthreads();
        #pragma unroll
        for (int i = 0; i < 2; ++i) {
            int c = (i << 8) + tid;
            int row = c >> 2, u = c & 3;
            stage16(&A[(size_t)(row0 + row) * EMB + k0 + (u << 3)],
                    (char*)As + (i << 12) + (w << 10), lane);
            stage16(&Bt[(size_t)(col0 + row) * EMB + k0 + (u << 3)],
                    (char*)Bs + (i << 12) + (w << 10), lane);
        }
        __syncthreads();

        f16x8 af[4], bf[4];
        #pragma unroll
        for (int mt = 0; mt < 4; ++mt)
            af[mt] = *(const f16x8*)((const char*)As +
                     ((wm << 6) + (mt << 4) + l15) * 64 + (g4 << 4));
        #pragma unroll
        for (int nt = 0; nt < 4; ++nt)
            bf[nt] = *(const f16x8*)((const char*)Bs +
                     ((wn << 6) + (nt << 4) + l15) * 64 + (g4 << 4));
        #pragma unroll
        for (int mt = 0; mt < 4; ++mt)
            #pragma unroll
            for (int nt = 0; nt < 4; ++nt)
                acc[mt][nt] = __builtin_amdgcn_mfma_f32_16x16x32_f16(
                    af[mt], bf[nt], acc[mt][nt], 0, 0, 0);
    }

    // Epilogue. C/D: col = lane&15, row = 4*(lane>>4) + reg.
    #pragma unroll
    for (int mt = 0; mt < 4; ++mt) {
        int m = row0 + (wm << 6) + (mt << 4) + (g4 << 2);
        #pragma unroll
        for (int nt = 0; nt < 4; ++nt) {
            int gcol = col0 + (wn << 6) + (nt << 4) + l15;
            int proj = gcol >> 10, pc = gcol & 1023;
            int h = pc >> 6, d = pc & 63;
            int b = m >> 11, tt = m & 2047;
            int bh = b * NUM_HEADS + h;
            if (proj == 2) {
                f16x4 v4;
                v4[0] = (_Float16)acc[mt][nt][0];
                v4[1] = (_Float16)acc[mt][nt][1];
                v4[2] = (_Float16)acc[mt][nt][2];
                v4[3] = (_Float16)acc[mt][nt][3];
                *(f16x4*)&VhT[((size_t)bh * HEAD_D + d) * SEQ + tt] = v4;
            } else {
                _Float16* dst = proj == 0 ? Qh : Kh;
                float alpha = proj == 0 ? QALPHA : 1.0f;
                #pragma unroll
                for (int r = 0; r < 4; ++r)
                    dst[((size_t)bh * SEQ + tt + r) * HEAD_D + d] =
                        (_Float16)(acc[mt][nt][r] * alpha);
            }
        }
    }
}

// ---------------------------------------------------------------------------
// Output projection GEMM: [4096, 1024] fp32 + bias. 128x64 tile (512 blocks
// = 2/CU), BK=32 (R19 form), 4 waves, wave tile 64x32. XCD swizzle.
// ---------------------------------------------------------------------------
__global__ __launch_bounds__(256) void gemm_out(
    const _Float16* __restrict__ A, const _Float16* __restrict__ Bt,
    float* __restrict__ outf, const float* __restrict__ bias)
{
    __shared__ __align__(16) _Float16 As[128 * 32]; // 8 KB
    __shared__ __align__(16) _Float16 Bs[64 * 32];  // 4 KB

    const int tid = threadIdx.x;
    const int w = tid >> 6, lane = tid & 63;
    const int l15 = lane & 15, g4 = lane >> 4;
    const int wm = w >> 1, wn = w & 1;

    const int wg = blockIdx.y * gridDim.x + blockIdx.x;
    const int t  = (wg & 7) * 64 + (wg >> 3);
    const int bx = t >> 5, by = t & 31;
    const int row0 = by * 128, col0 = bx * 64;

    f32x4 acc[4][2];
    #pragma unroll
    for (int mt = 0; mt < 4; ++mt)
        #pragma unroll
        for (int nt = 0; nt < 2; ++nt)
            acc[mt][nt] = (f32x4){0.f, 0.f, 0.f, 0.f};

    for (int k0 = 0; k0 < EMB; k0 += 32) {
        __syncthreads();
        #pragma unroll
        for (int i = 0; i < 2; ++i) {
            int c = (i << 8) + tid;
            int row = c >> 2, u = c & 3;
            stage16(&A[(size_t)(row0 + row) * EMB + k0 + (u << 3)],
                    (char*)As + (i << 12) + (w << 10), lane);
        }
        {
            int row = tid >> 2, u = tid & 3; // 256 chunks: 64 rows x 4 units
            stage16(&Bt[(size_t)(col0 + row) * EMB + k0 + (u << 3)],
                    (char*)Bs + (w << 10), lane);
        }
        __syncthreads();

        f16x8 af[4], bf[2];
        #pragma unroll
        for (int mt = 0; mt < 4; ++mt)
            af[mt] = *(const f16x8*)((const char*)As +
                     ((wm << 6) + (mt << 4) + l15) * 64 + (g4 << 4));
        #pragma unroll
        for (int nt = 0; nt < 2; ++nt)
            bf[nt] = *(const f16x8*)((const char*)Bs +
                     ((wn << 5) + (nt << 4) + l15) * 64 + (g4 << 4));
        #pragma unroll
        for (int mt = 0; mt < 4; ++mt)
            #pragma unroll
            for (int nt = 0; nt < 2; ++nt)
                acc[mt][nt] = __builtin_amdgcn_mfma_f32_16x16x32_f16(
                    af[mt], bf[nt], acc[mt][nt], 0, 0, 0);
    }

    #pragma unroll
    for (int mt = 0; mt < 4; ++mt) {
        int m = row0 + (wm << 6) + (mt << 4) + (g4 << 2);
        #pragma unroll
        for (int nt = 0; nt < 2; ++nt) {
            int gcol = col0 + (wn << 5) + (nt << 4) + l15;
            float bz = bias[gcol];
            #pragma unroll
            for (int r = 0; r < 4; ++r)
                outf[(size_t)(m + r) * EMB + gcol] = acc[mt][nt][r] + bz;
        }
    }
}

// ---------------------------------------------------------------------------
// Stage one 64-kv K tile + V^T tile into LDS via global_load_lds with
// pre-swizzled global source (LDS dest linear; chunk (row,u) holds global
// (row, u^(row&7)) -> read formulas identical to the verified K-frag path).
// ---------------------------------------------------------------------------
__device__ __forceinline__ void stage_kv_tile(
    const _Float16* __restrict__ KhB, const _Float16* __restrict__ VtB,
    int kv0, char* __restrict__ KsBuf, char* __restrict__ VtBuf,
    int w, int lane)
{
    #pragma unroll
    for (int i = 0; i < 2; ++i) {
        int c = (i << 8) + (w << 6) + lane;
        int row = c >> 3, u = c & 7;
        int us = u ^ (row & 7);
        stage16(&KhB[(size_t)(kv0 + row) * HEAD_D + (us << 3)],
                KsBuf + (i << 12) + (w << 10), lane);
        stage16(&VtB[(size_t)row * SEQ + kv0 + (us << 3)],
                VtBuf + (i << 12) + (w << 10), lane);
    }
}

// ---------------------------------------------------------------------------
// Single 64q x 64kv attention tile step (verified R15 form): S^T = K Q^T,
// shuffle-free defer-max softmax, per-lane partial l, P roundtrip, PV.
// ---------------------------------------------------------------------------
__device__ __forceinline__ void attn_tile(
    const char* __restrict__ KsC, const char* __restrict__ VtC,
    char* __restrict__ pwv,
    f16x8 qf0, f16x8 qf1, f32x4 (&acc)[4], float& m, float& l,
    bool diag, int qrel, int l15, int g)
{
    f32x4 st[4];
    #pragma unroll
    for (int nt = 0; nt < 4; ++nt) {
        int kvl = (nt << 4) + l15;
        f16x8 kf0 = *(const f16x8*)&KsC[kvl * 128 + (((g << 4)) ^ ((kvl & 7) << 4))];
        f16x8 kf1 = *(const f16x8*)&KsC[kvl * 128 + ((64 + (g << 4)) ^ ((kvl & 7) << 4))];
        f32x4 z = (f32x4){0.f, 0.f, 0.f, 0.f};
        z = __builtin_amdgcn_mfma_f32_16x16x32_f16(kf0, qf0, z, 0, 0, 0);
        z = __builtin_amdgcn_mfma_f32_16x16x32_f16(kf1, qf1, z, 0, 0, 0);
        st[nt] = z;
    }
    if (diag) {
        #pragma unroll
        for (int nt = 0; nt < 4; ++nt)
            #pragma unroll
            for (int r = 0; r < 4; ++r)
                if ((nt << 4) + (g << 2) + r > qrel) st[nt][r] = -1e30f;
    }

    float mx;
    {
        float a0 = fmaxf(fmaxf(st[0][0], st[0][1]), fmaxf(st[0][2], st[0][3]));
        float a1 = fmaxf(fmaxf(st[1][0], st[1][1]), fmaxf(st[1][2], st[1][3]));
        float a2 = fmaxf(fmaxf(st[2][0], st[2][1]), fmaxf(st[2][2], st[2][3]));
        float a3 = fmaxf(fmaxf(st[3][0], st[3][1]), fmaxf(st[3][2], st[3][3]));
        mx = fmaxf(fmaxf(a0, a1), fmaxf(a2, a3));
    }

    if (!__all(mx - m <= 8.0f)) {
        float mxr = fmaxf(mx, __shfl_xor(mx, 16));
        mxr = fmaxf(mxr, __shfl_xor(mxr, 32));
        float nm = fmaxf(m, mxr);
        float sc = fast_exp2(m - nm);   // row-uniform
        m = nm;
        l *= sc;
        #pragma unroll
        for (int r = 0; r < 4; ++r) {
            float scr = __shfl(sc, (g << 2) + r);
            acc[0][r] *= scr; acc[1][r] *= scr;
            acc[2][r] *= scr; acc[3][r] *= scr;
        }
    }

    float ps = 0.f;
    #pragma unroll
    for (int nt = 0; nt < 4; ++nt)
        #pragma unroll
        for (int r = 0; r < 4; ++r) {
            float p = fast_exp2(st[nt][r] - m);
            st[nt][r] = p;
            ps += p;
        }
    l += ps;

    #pragma unroll
    for (int nt = 0; nt < 4; ++nt)
        #pragma unroll
        for (int rr = 0; rr < 2; ++rr) {
            int kvb = (nt << 4) + (g << 2) + (rr << 1);
            f16x2 pv = cvt_pk_f16(st[nt][rr * 2], st[nt][rr * 2 + 1]);
            *(f16x2*)&pwv[l15 * 128 + ((kvb << 1) ^ ((l15 & 7) << 4))] = pv;
        }
    f16x8 pa0 = *(const f16x8*)&pwv[l15 * 128 + (((g << 4)) ^ ((l15 & 7) << 4))];
    f16x8 pa1 = *(const f16x8*)&pwv[l15 * 128 + ((64 + (g << 4)) ^ ((l15 & 7) << 4))];

    #pragma unroll
    for (int dn = 0; dn < 4; ++dn) {
        int d = (dn << 4) + l15;
        f16x8 vf0 = *(const f16x8*)&VtC[d * 128 + (((g << 4)) ^ ((d & 7) << 4))];
        f16x8 vf1 = *(const f16x8*)&VtC[d * 128 + ((64 + (g << 4)) ^ ((d & 7) << 4))];
        acc[dn] = __builtin_amdgcn_mfma_f32_16x16x32_f16(pa0, vf0, acc[dn], 0, 0, 0);
        acc[dn] = __builtin_amdgcn_mfma_f32_16x16x32_f16(pa1, vf1, acc[dn], 0, 0, 0);
    }
}

// ---------------------------------------------------------------------------
// Dual-chain single-kv step (R22, measured best): shared K/V fragments feed
// both chains' MFMAs. diag applies to A only.
// ---------------------------------------------------------------------------
__device__ __forceinline__ void attn_tile_dual(
    const char* __restrict__ KsC, const char* __restrict__ VtC,
    char* __restrict__ pwvA, char* __restrict__ pwvB,
    f16x8 qfA0, f16x8 qfA1, f16x8 qfB0, f16x8 qfB1,
    f32x4 (&accA)[4], f32x4 (&accB)[4],
    float& mA, float& lA, float& mB, float& lB,
    bool diagA, int qrel, int l15, int g)
{
    f32x4 sA[4], sB[4];
    #pragma unroll
    for (int nt = 0; nt < 4; ++nt) {
        int kvl = (nt << 4) + l15;
        f16x8 kf0 = *(const f16x8*)&KsC[kvl * 128 + (((g << 4)) ^ ((kvl & 7) << 4))];
        f16x8 kf1 = *(const f16x8*)&KsC[kvl * 128 + ((64 + (g << 4)) ^ ((kvl & 7) << 4))];
        f32x4 zA = (f32x4){0.f, 0.f, 0.f, 0.f};
        zA = __builtin_amdgcn_mfma_f32_16x16x32_f16(kf0, qfA0, zA, 0, 0, 0);
        zA = __builtin_amdgcn_mfma_f32_16x16x32_f16(kf1, qfA1, zA, 0, 0, 0);
        sA[nt] = zA;
        f32x4 zB = (f32x4){0.f, 0.f, 0.f, 0.f};
        zB = __builtin_amdgcn_mfma_f32_16x16x32_f16(kf0, qfB0, zB, 0, 0, 0);
        zB = __builtin_amdgcn_mfma_f32_16x16x32_f16(kf1, qfB1, zB, 0, 0, 0);
        sB[nt] = zB;
    }
    if (diagA) {
        #pragma unroll
        for (int nt = 0; nt < 4; ++nt)
            #pragma unroll
            for (int r = 0; r < 4; ++r)
                if ((nt << 4) + (g << 2) + r > qrel) sA[nt][r] = -1e30f;
    }

    // softmax A
    {
        float a0 = fmaxf(fmaxf(sA[0][0], sA[0][1]), fmaxf(sA[0][2], sA[0][3]));
        float a1 = fmaxf(fmaxf(sA[1][0], sA[1][1]), fmaxf(sA[1][2], sA[1][3]));
        float a2 = fmaxf(fmaxf(sA[2][0], sA[2][1]), fmaxf(sA[2][2], sA[2][3]));
        float a3 = fmaxf(fmaxf(sA[3][0], sA[3][1]), fmaxf(sA[3][2], sA[3][3]));
        float mx = fmaxf(fmaxf(a0, a1), fmaxf(a2, a3));
        if (!__all(mx - mA <= 8.0f)) {
            float mxr = fmaxf(mx, __shfl_xor(mx, 16));
            mxr = fmaxf(mxr, __shfl_xor(mxr, 32));
            float nm = fmaxf(mA, mxr);
            float sc = fast_exp2(mA - nm);
            mA = nm;
            lA *= sc;
            #pragma unroll
            for (int r = 0; r < 4; ++r) {
                float scr = __shfl(sc, (g << 2) + r);
                accA[0][r] *= scr; accA[1][r] *= scr;
                accA[2][r] *= scr; accA[3][r] *= scr;
            }
        }
        float ps = 0.f;
        #pragma unroll
        for (int nt = 0; nt < 4; ++nt)
            #pragma unroll
            for (int r = 0; r < 4; ++r) {
                float p = fast_exp2(sA[nt][r] - mA);
                sA[nt][r] = p;
                ps += p;
            }
        lA += ps;
    }
    // softmax B
    {
        float a0 = fmaxf(fmaxf(sB[0][0], sB[0][1]), fmaxf(sB[0][2], sB[0][3]));
        float a1 = fmaxf(fmaxf(sB[1][0], sB[1][1]), fmaxf(sB[1][2], sB[1][3]));
        float a2 = fmaxf(fmaxf(sB[2][0], sB[2][1]), fmaxf(sB[2][2], sB[2][3]));
        float a3 = fmaxf(fmaxf(sB[3][0], sB[3][1]), fmaxf(sB[3][2], sB[3][3]));
        float mx = fmaxf(fmaxf(a0, a1), fmaxf(a2, a3));
        if (!__all(mx - mB <= 8.0f)) {
            float mxr = fmaxf(mx, __shfl_xor(mx, 16));
            mxr = fmaxf(mxr, __shfl_xor(mxr, 32));
            float nm = fmaxf(mB, mxr);
            float sc = fast_exp2(mB - nm);
            mB = nm;
            lB *= sc;
            #pragma unroll
            for (int r = 0; r < 4; ++r) {
                float scr = __shfl(sc, (g << 2) + r);
                accB[0][r] *= scr; accB[1][r] *= scr;
                accB[2][r] *= scr; accB[3][r] *= scr;
            }
        }
        float ps = 0.f;
        #pragma unroll
        for (int nt = 0; nt < 4; ++nt)
            #pragma unroll
            for (int r = 0; r < 4; ++r) {
                float p = fast_exp2(sB[nt][r] - mB);
                sB[nt][r] = p;
                ps += p;
            }
        lB += ps;
    }

    // P writes for both chains (independent regions)
    #pragma unroll
    for (int nt = 0; nt < 4; ++nt)
        #pragma unroll
        for (int rr = 0; rr < 2; ++rr) {
            int kvb = (nt << 4) + (g << 2) + (rr << 1);
            int off = l15 * 128 + ((kvb << 1) ^ ((l15 & 7) << 4));
            *(f16x2*)&pwvA[off] = cvt_pk_f16(sA[nt][rr * 2], sA[nt][rr * 2 + 1]);
            *(f16x2*)&pwvB[off] = cvt_pk_f16(sB[nt][rr * 2], sB[nt][rr * 2 + 1]);
        }
    int poff0 = l15 * 128 + (((g << 4)) ^ ((l15 & 7) << 4));
    int poff1 = l15 * 128 + ((64 + (g << 4)) ^ ((l15 & 7) << 4));
    f16x8 paA0 = *(const f16x8*)&pwvA[poff0];
    f16x8 paA1 = *(const f16x8*)&pwvA[poff1];
    f16x8 paB0 = *(const f16x8*)&pwvB[poff0];
    f16x8 paB1 = *(const f16x8*)&pwvB[poff1];

    // PV: shared V fragments feed both chains
    #pragma unroll
    for (int dn = 0; dn < 4; ++dn) {
        int d = (dn << 4) + l15;
        f16x8 vf0 = *(const f16x8*)&VtC[d * 128 + (((g << 4)) ^ ((d & 7) << 4))];
        f16x8 vf1 = *(const f16x8*)&VtC[d * 128 + ((64 + (g << 4)) ^ ((d & 7) << 4))];
        accA[dn] = __builtin_amdgcn_mfma_f32_16x16x32_f16(paA0, vf0, accA[dn], 0, 0, 0);
        accA[dn] = __builtin_amdgcn_mfma_f32_16x16x32_f16(paA1, vf1, accA[dn], 0, 0, 0);
        accB[dn] = __builtin_amdgcn_mfma_f32_16x16x32_f16(paB0, vf0, accB[dn], 0, 0, 0);
        accB[dn] = __builtin_amdgcn_mfma_f32_16x16x32_f16(paB1, vf1, accB[dn], 0, 0, 0);
    }
}

// ---------------------------------------------------------------------------
// Dual-kv tile step for one chain: QK over BOTH tiles, ONE merged softmax
// pass, two P->PV steps with separate P regions. diag only on SECOND tile.
// ---------------------------------------------------------------------------
__device__ __forceinline__ void attn_tile2(
    const char* __restrict__ Ks0, const char* __restrict__ Vt0,
    const char* __restrict__ Ks1, const char* __restrict__ Vt1,
    char* __restrict__ pwv0, char* __restrict__ pwv1,
    f16x8 qf0, f16x8 qf1, f32x4 (&acc)[4], float& m, float& l,
    bool diag1, int qrel, int l15, int g)
{
    f32x4 st[8];
    #pragma unroll
    for (int nt = 0; nt < 4; ++nt) {
        int kvl = (nt << 4) + l15;
        int off0 = kvl * 128 + (((g << 4)) ^ ((kvl & 7) << 4));
        int off1 = kvl * 128 + ((64 + (g << 4)) ^ ((kvl & 7) << 4));
        f16x8 ka0 = *(const f16x8*)&Ks0[off0];
        f16x8 ka1 = *(const f16x8*)&Ks0[off1];
        f32x4 z = (f32x4){0.f, 0.f, 0.f, 0.f};
        z = __builtin_amdgcn_mfma_f32_16x16x32_f16(ka0, qf0, z, 0, 0, 0);
        z = __builtin_amdgcn_mfma_f32_16x16x32_f16(ka1, qf1, z, 0, 0, 0);
        st[nt] = z;
        f16x8 kb0 = *(const f16x8*)&Ks1[off0];
        f16x8 kb1 = *(const f16x8*)&Ks1[off1];
        f32x4 z2 = (f32x4){0.f, 0.f, 0.f, 0.f};
        z2 = __builtin_amdgcn_mfma_f32_16x16x32_f16(kb0, qf0, z2, 0, 0, 0);
        z2 = __builtin_amdgcn_mfma_f32_16x16x32_f16(kb1, qf1, z2, 0, 0, 0);
        st[4 + nt] = z2;
    }
    if (diag1) {
        #pragma unroll
        for (int nt = 0; nt < 4; ++nt)
            #pragma unroll
            for (int r = 0; r < 4; ++r)
                if ((nt << 4) + (g << 2) + r > qrel) st[4 + nt][r] = -1e30f;
    }

    float mx;
    {
        float a = -1e30f;
        #pragma unroll
        for (int i = 0; i < 8; ++i)
            a = fmaxf(a, fmaxf(fmaxf(st[i][0], st[i][1]),
                               fmaxf(st[i][2], st[i][3])));
        mx = a;
    }

    if (!__all(mx - m <= 8.0f)) {
        float mxr = fmaxf(mx, __shfl_xor(mx, 16));
        mxr = fmaxf(mxr, __shfl_xor(mxr, 32));
        float nm = fmaxf(m, mxr);
        float sc = fast_exp2(m - nm);
        m = nm;
        l *= sc;
        #pragma unroll
        for (int r = 0; r < 4; ++r) {
            float scr = __shfl(sc, (g << 2) + r);
            acc[0][r] *= scr; acc[1][r] *= scr;
            acc[2][r] *= scr; acc[3][r] *= scr;
        }
    }

    float ps = 0.f;
    #pragma unroll
    for (int i = 0; i < 8; ++i)
        #pragma unroll
        for (int r = 0; r < 4; ++r) {
            float p = fast_exp2(st[i][r] - m);
            st[i][r] = p;
            ps += p;
        }
    l += ps;

    // PV tile 0 -> pwv0, tile 1 -> pwv1 (independent regions)
    #pragma unroll
    for (int tile = 0; tile < 2; ++tile) {
        const f32x4* s4 = &st[tile << 2];
        const char* Vt = tile ? Vt1 : Vt0;
        char* pwv = tile ? pwv1 : pwv0;
        #pragma unroll
        for (int nt = 0; nt < 4; ++nt)
            #pragma unroll
            for (int rr = 0; rr < 2; ++rr) {
                int kvb = (nt << 4) + (g << 2) + (rr << 1);
                f16x2 pv = cvt_pk_f16(s4[nt][rr * 2], s4[nt][rr * 2 + 1]);
                *(f16x2*)&pwv[l15 * 128 + ((kvb << 1) ^ ((l15 & 7) << 4))] = pv;
            }
        f16x8 pa0 = *(const f16x8*)&pwv[l15 * 128 + (((g << 4)) ^ ((l15 & 7) << 4))];
        f16x8 pa1 = *(const f16x8*)&pwv[l15 * 128 + ((64 + (g << 4)) ^ ((l15 & 7) << 4))];
        #pragma unroll
        for (int dn = 0; dn < 4; ++dn) {
            int d = (dn << 4) + l15;
            f16x8 vf0 = *(const f16x8*)&Vt[d * 128 + (((g << 4)) ^ ((d & 7) << 4))];
            f16x8 vf1 = *(const f16x8*)&Vt[d * 128 + ((64 + (g << 4)) ^ ((d & 7) << 4))];
            acc[dn] = __builtin_amdgcn_mfma_f32_16x16x32_f16(pa0, vf0, acc[dn], 0, 0, 0);
            acc[dn] = __builtin_amdgcn_mfma_f32_16x16x32_f16(pa1, vf1, acc[dn], 0, 0, 0);
        }
    }
}

// ---------------------------------------------------------------------------
// Flash attention, causal, fp16 MFMA. Paired q-tiles (qtA, 31-qtA) with
// UNIFORM 17 iterations per block. XCD-aware swizzle (each XCD owns 4 heads,
// K/V L2-resident: FETCH 67->12.4 MB measured). Phase 1 uses the shared-
// fragment dual-chain step.
// ---------------------------------------------------------------------------
__global__ __launch_bounds__(256, 4) void attn_mfma(
    const _Float16* __restrict__ Qh, const _Float16* __restrict__ Kh,
    const _Float16* __restrict__ VhT, _Float16* __restrict__ O)
{
    __shared__ char lds[80 * 1024];
#define KSLOT(s) (lds + ((s) << 13))
#define VSLOT(s) (lds + 32768 + ((s) << 13))

    // XCD swizzle: wg -> (qtA, bh). Bijective over 512 = 8 xcd x 4 bh x 16 qt.
    const int wg  = blockIdx.y * gridDim.x + blockIdx.x;
    const int idx = wg >> 3;                       // 0..63
    const int bh  = (wg & 7) * 4 + (idx >> 4);     // 4 heads per XCD slot
    const int qtA = idx & 15;                      // 0..15
    const int qtB = (SEQ / 64 - 1) - qtA;          // 31..16
    const int q0A = qtA << 6, q0B = qtB << 6;
    const int tid = threadIdx.x;
    const int w = tid >> 6, lane = tid & 63;
    const int l15 = lane & 15, g = lane >> 4;

    const _Float16* KhB = Kh  + (size_t)bh * SEQ * HEAD_D;
    const _Float16* VtB = VhT + (size_t)bh * HEAD_D * SEQ;
    const size_t headbase = (size_t)bh * SEQ * HEAD_D;

    const int qrowA = q0A + (w << 4) + l15;
    const int qrowB = q0B + (w << 4) + l15;
    f16x8 qfA0 = *(const f16x8*)&Qh[headbase + (size_t)qrowA * HEAD_D + (g << 3)];
    f16x8 qfA1 = *(const f16x8*)&Qh[headbase + (size_t)qrowA * HEAD_D + 32 + (g << 3)];
    f16x8 qfB0 = *(const f16x8*)&Qh[headbase + (size_t)qrowB * HEAD_D + (g << 3)];
    f16x8 qfB1 = *(const f16x8*)&Qh[headbase + (size_t)qrowB * HEAD_D + 32 + (g << 3)];

    f32x4 accA[4], accB[4];
    #pragma unroll
    for (int dn = 0; dn < 4; ++dn) {
        accA[dn] = (f32x4){0.f, 0.f, 0.f, 0.f};
        accB[dn] = (f32x4){0.f, 0.f, 0.f, 0.f};
    }
    float mA = -1e30f, lA = 0.f, mB = -1e30f, lB = 0.f;

    // ---- prologue: stage tiles 0 and 1 ----
    stage_kv_tile(KhB, VtB, 0,  KSLOT(0), VSLOT(0), w, lane);
    stage_kv_tile(KhB, VtB, 64, KSLOT(1), VSLOT(1), w, lane);
    __syncthreads();

    char* pwvA = lds + 65536 + (w << 11);
    char* pwvB = lds + 73728 + (w << 11);
    const int qrel = (w << 4) + l15;

    // ---- phase 1: kt = 0..qtA, shared kv, dual chains (shared K/V frags) ----
    for (int kt = 0; kt <= qtA; ++kt) {
        int pf = kt + 2;
        if (pf <= qtB)
            stage_kv_tile(KhB, VtB, pf << 6, KSLOT(pf & 3), VSLOT(pf & 3), w, lane);
        attn_tile_dual(KSLOT(kt & 3), VSLOT(kt & 3), pwvA, pwvB,
                       qfA0, qfA1, qfB0, qfB1, accA, accB,
                       mA, lA, mB, lB, kt == qtA, qrel, l15, g);
        __syncthreads();
    }

    // ---- phase 2 head: single B tile at kt = qtA+1 (diag iff == qtB) ----
    {
        int kt = qtA + 1;
        int pf = kt + 2;
        if (pf <= qtB)
            stage_kv_tile(KhB, VtB, pf << 6, KSLOT(pf & 3), VSLOT(pf & 3), w, lane);
        attn_tile(KSLOT(kt & 3), VSLOT(kt & 3), pwvB, qfB0, qfB1, accB, mB, lB,
                  kt == qtB, qrel, l15, g);
        __syncthreads();
    }

    // ---- phase 2 pairs: kt = qtA+2, step 2, through qtB ----
    for (int kt = qtA + 2; kt < qtB; kt += 2) {
        int pf0 = kt + 2, pf1 = kt + 3;
        if (pf0 <= qtB)
            stage_kv_tile(KhB, VtB, pf0 << 6, KSLOT(pf0 & 3), VSLOT(pf0 & 3), w, lane);
        if (pf1 <= qtB)
            stage_kv_tile(KhB, VtB, pf1 << 6, KSLOT(pf1 & 3), VSLOT(pf1 & 3), w, lane);
        attn_tile2(KSLOT(kt & 3), VSLOT(kt & 3),
                   KSLOT((kt + 1) & 3), VSLOT((kt + 1) & 3),
                   pwvB, pwvA, qfB0, qfB1, accB, mB, lB,
                   (kt + 1) == qtB, qrel, l15, g);
        __syncthreads();
    }

    // ---- epilogue: deferred l reduction, normalize, store ----
    lA += __shfl_xor(lA, 16); lA += __shfl_xor(lA, 32);
    lB += __shfl_xor(lB, 16); lB += __shfl_xor(lB, 32);
    const int b = bh >> 4, h = bh & 15;
    const float rlA = 1.f / lA, rlB = 1.f / lB;
    #pragma unroll
    for (int r = 0; r < 4; ++r) {
        float invA = __shfl(rlA, (g << 2) + r);
        float invB = __shfl(rlB, (g << 2) + r);
        int tokA = (b << 11) + q0A + (w << 4) + (g << 2) + r;
        int tokB = (b << 11) + q0B + (w << 4) + (g << 2) + r;
        #pragma unroll
        for (int dn = 0; dn < 4; ++dn) {
            O[(size_t)tokA * EMB + (h << 6) + (dn << 4) + l15] =
                (_Float16)(accA[dn][r] * invA);
            O[(size_t)tokB * EMB + (h << 6) + (dn << 4) + l15] =
                (_Float16)(accB[dn][r] * invB);
        }
    }
#undef KSLOT
#undef VSLOT
}

// ---------------------------------------------------------------------------
extern "C" void kernel_launch(void* const* d_in, const int* in_sizes, int n_in,
                              void* d_out, int out_size, void* d_ws, size_t ws_size,
                              hipStream_t stream)
{
    const float* x  = (const float*)d_in[0];
    const float* Wq = (const float*)d_in[1];
    const float* Wk = (const float*)d_in[2];
    const float* Wv = (const float*)d_in[3];
    const float* Wo = (const float*)d_in[4];
    const float* bo = (const float*)d_in[5];
    float* out = (float*)d_out;

    const size_t ME = (size_t)MTOT * EMB;        // 4M elems
    const size_t WE = (size_t)EMB * EMB;         // 1M elems
    const size_t need = (5 * ME + 4 * WE) * sizeof(_Float16);
    if (ws_size < need) return;

    _Float16* xh  = (_Float16*)d_ws;
    _Float16* Wt  = xh + ME;
    _Float16* Wto = Wt + 3 * WE;
    _Float16* Qh  = Wto + WE;
    _Float16* Kh  = Qh + ME;
    _Float16* VhT = Kh + ME;   // V stored transposed [B,H,D,T] by the GEMM
    _Float16* Ow  = VhT + ME;

    prep_all<<<dim3(EMB / 32, EMB / 32, 5), 256, 0, stream>>>(
        x, Wq, Wk, Wv, Wo, xh, Wt, Wto);

    gemm_qkv<<<dim3(3 * EMB / 128, MTOT / 128), 256, 0, stream>>>(
        xh, Wt, Qh, Kh, VhT);

    attn_mfma<<<dim3(SEQ / 128, BATCH * NUM_HEADS), 256, 0, stream>>>(Qh, Kh, VhT, Ow);

    gemm_out<<<dim3(EMB / 64, MTOT / 128), 256, 0, stream>>>(
        Ow, Wto, out, bo);
}